// Round 3
// baseline (287.638 us; speedup 1.0000x reference)
//
#include <hip/hip_runtime.h>
#include <hip/hip_bf16.h>

typedef __attribute__((ext_vector_type(4))) float f32x4;
typedef __attribute__((ext_vector_type(8))) short s16x8;
typedef __attribute__((ext_vector_type(4))) short s16x4;
using bf16 = __hip_bfloat16;

static constexpr int BB  = 4;
static constexpr int SQ  = 512;
static constexpr int SKV = 2048;
static constexpr int SKT = 512;
static constexpr int DIM = 1024;
static constexpr int NH  = 16;
static constexpr int HD  = 64;

#define MFMA32(A,B,C) __builtin_amdgcn_mfma_f32_16x16x32_bf16(A,B,C,0,0,0)

#if __has_builtin(__builtin_amdgcn_mfma_f32_16x16x16_bf16)
  #define MFMA16(A,B,C) __builtin_amdgcn_mfma_f32_16x16x16_bf16(A,B,C,0,0,0)
  #define HAVE_X16 1
#elif __has_builtin(__builtin_amdgcn_mfma_f32_16x16x16bf16_1k)
  #define MFMA16(A,B,C) __builtin_amdgcn_mfma_f32_16x16x16bf16_1k(A,B,C,0,0,0)
  #define HAVE_X16 1
#else
  #define HAVE_X16 0
#endif

__device__ __forceinline__ float b2f(short s) {
  unsigned int u = ((unsigned int)(unsigned short)s) << 16;
  float f; __builtin_memcpy(&f, &u, 4); return f;
}
__device__ __forceinline__ short f2s(float f) {
  bf16 h = __float2bfloat16(f); short s; __builtin_memcpy(&s, &h, 2); return s;
}
__device__ __forceinline__ unsigned int pack2(float a, float b) {
  const unsigned short lo = (unsigned short)f2s(a), hi = (unsigned short)f2s(b);
  return ((unsigned int)hi << 16) | lo;
}

__device__ __forceinline__ void gload16(const void* g, void* l) {
  __builtin_amdgcn_global_load_lds(
      (const __attribute__((address_space(1))) void*)g,
      (__attribute__((address_space(3))) void*)l, 16, 0, 0);
}

// ---------------- weight cast f32 -> bf16 (batched via grid.y) --------------
struct CastArgs { const float* src[10]; bf16* dst[10]; int n[10]; };
__global__ __launch_bounds__(256) void cast_kernel(CastArgs a) {
  const int y = blockIdx.y;
  const int n = a.n[y];
  const int i = (blockIdx.x * 256 + threadIdx.x) * 4;
  if (i >= n) return;
  const float4 v = *(const float4*)(a.src[y] + i);
  bf16* d = a.dst[y] + i;
  d[0] = __float2bfloat16(v.x); d[1] = __float2bfloat16(v.y);
  d[2] = __float2bfloat16(v.z); d[3] = __float2bfloat16(v.w);
}

// ---------------- RMSNorm (f32 in, bf16 out), one block per row -------------
struct NormArgs { const float* x[3]; const float* w[3]; bf16* y[3]; int rows[3]; };
__global__ __launch_bounds__(256) void rmsnorm_kernel(NormArgs a) {
  const int t = blockIdx.y, row = blockIdx.x;
  if (row >= a.rows[t]) return;
  const float* x = a.x[t] + (size_t)row * DIM;
  const float4 v = *(const float4*)(x + threadIdx.x * 4);
  float ss = v.x*v.x + v.y*v.y + v.z*v.z + v.w*v.w;
  #pragma unroll
  for (int m = 32; m >= 1; m >>= 1) ss += __shfl_xor(ss, m);
  __shared__ float red[4];
  if ((threadIdx.x & 63) == 0) red[threadIdx.x >> 6] = ss;
  __syncthreads();
  ss = red[0] + red[1] + red[2] + red[3];
  const float sc = rsqrtf(ss * (1.0f / DIM) + 1.1920928955078125e-07f);
  const float4 w = *(const float4*)(a.w[t] + threadIdx.x * 4);
  bf16* y = a.y[t] + (size_t)row * DIM + threadIdx.x * 4;
  y[0] = __float2bfloat16(v.x * sc * w.x);
  y[1] = __float2bfloat16(v.y * sc * w.y);
  y[2] = __float2bfloat16(v.z * sc * w.z);
  y[3] = __float2bfloat16(v.w * sc * w.w);
}

// ---------------- GEMM: C = act(A @ W^T + bias), slot-batched ----------------
// m97 structure: 128x128 tile, BK=32, single-buffered 16 KB LDS,
// stage -> barrier -> 16 MFMA -> barrier. 16B-granule XOR swizzle both sides.
// epi 0: bf16 token-major; 1: silu bf16; 2: f32 + resid;
// epi 3: bf16 head-major * QSCALE (Q); 4: bf16 head-major (K).
struct GSlot { const bf16* A; const bf16* W; const float* bias;
               const float* resid; bf16* Cb; float* Cf; int epi; int sksh; };
struct GArgs { GSlot s[4]; };

static constexpr float QSCALE = 0.180336880111120426f;  // 0.125 * log2(e)

__global__ __launch_bounds__(256) void gemm_sb(GArgs a) {
  constexpr int K = DIM;
  __shared__ alignas(16) char sA[8192];
  __shared__ alignas(16) char sB[8192];
  const GSlot S = a.s[blockIdx.z];
  const int tid = threadIdx.x, lane = tid & 63, wave = tid >> 6;
  const int bm = blockIdx.x, bn = blockIdx.y;
  const int wm = wave >> 1, wn = wave & 1;
  const int m16 = lane & 15, g16 = lane >> 4;

  f32x4 acc[4][4];
  #pragma unroll
  for (int i = 0; i < 4; ++i)
    #pragma unroll
    for (int j = 0; j < 4; ++j)
      #pragma unroll
      for (int r = 0; r < 4; ++r) acc[i][j][r] = 0.0f;

  const bf16* Ab = S.A + (size_t)bm * 128 * K;
  const bf16* Wb = S.W + (size_t)bn * 128 * K;

  for (int t = 0; t < K / 32; ++t) {
    const int k0 = t * 32;
    #pragma unroll
    for (int p = 0; p < 2; ++p) {
      const int idx = p * 256 + tid;
      const int row = idx >> 2, sg = (idx & 3) ^ (row & 3);
      const size_t so = (size_t)row * K + k0 + sg * 8;
      gload16(Ab + so, &sA[p * 4096 + wave * 1024]);
      gload16(Wb + so, &sB[p * 4096 + wave * 1024]);
    }
    __syncthreads();
    s16x8 af[4], bfr[4];
    #pragma unroll
    for (int mi = 0; mi < 4; ++mi) {
      const int row = wm * 64 + mi * 16 + m16;
      af[mi] = *(const s16x8*)(&sA[row * 64 + (g16 ^ (m16 & 3)) * 16]);
    }
    #pragma unroll
    for (int ni = 0; ni < 4; ++ni) {
      const int row = wn * 64 + ni * 16 + m16;
      bfr[ni] = *(const s16x8*)(&sB[row * 64 + (g16 ^ (m16 & 3)) * 16]);
    }
    #pragma unroll
    for (int mi = 0; mi < 4; ++mi)
      #pragma unroll
      for (int ni = 0; ni < 4; ++ni)
        acc[mi][ni] = MFMA32(af[mi], bfr[ni], acc[mi][ni]);
    __syncthreads();
  }

  const int r0 = bm * 128 + wm * 64, c0 = bn * 128 + wn * 64;
  if (S.epi >= 3) {
    const float sc = (S.epi == 3) ? QSCALE : 1.0f;
    const int msk = (1 << S.sksh) - 1;
    #pragma unroll
    for (int ni = 0; ni < 4; ++ni) {
      const int col = c0 + ni * 16 + m16;
      const int hh = col >> 6, d = col & 63;
      const float bv = S.bias[col];
      #pragma unroll
      for (int mi = 0; mi < 4; ++mi) {
        const int rowb = r0 + mi * 16 + g16 * 4;
        #pragma unroll
        for (int r = 0; r < 4; ++r) {
          const int m = rowb + r;
          const int bb2 = m >> S.sksh, tok = m & msk;
          S.Cb[(((size_t)(bb2 * NH + hh) << S.sksh) + tok) * HD + d] =
              __float2bfloat16((acc[mi][ni][r] + bv) * sc);
        }
      }
    }
  } else {
    #pragma unroll
    for (int ni = 0; ni < 4; ++ni) {
      const int col = c0 + ni * 16 + m16;
      const float bv = S.bias[col];
      #pragma unroll
      for (int mi = 0; mi < 4; ++mi) {
        const int rowb = r0 + mi * 16 + g16 * 4;
        #pragma unroll
        for (int r = 0; r < 4; ++r) {
          float v = acc[mi][ni][r] + bv;
          const size_t idx = (size_t)(rowb + r) * DIM + col;
          if (S.epi == 1)      { v = v / (1.0f + __expf(-v)); S.Cb[idx] = __float2bfloat16(v); }
          else if (S.epi == 2) { S.Cf[idx] = v + S.resid[idx]; }
          else                 { S.Cb[idx] = __float2bfloat16(v); }
        }
      }
    }
  }
}

// ---------------- gate GEMV: gate = sigmoid(g1 . w2 + b2), wave per row -----
__global__ __launch_bounds__(256) void gate_kernel(
    const bf16* __restrict__ g1, const bf16* __restrict__ w2,
    const float* __restrict__ b2, float* __restrict__ gate, int rows)
{
  const int lane = threadIdx.x & 63, wave = threadIdx.x >> 6;
  const int row = blockIdx.x * 4 + wave;
  if (row >= rows) return;
  const bf16* x = g1 + (size_t)row * DIM;
  float sum = 0.0f;
  #pragma unroll
  for (int c = 0; c < 2; ++c) {
    const int i0 = c * 512 + lane * 8;
    const s16x8 xv = *(const s16x8*)(x + i0);
    const s16x8 wv = *(const s16x8*)(w2 + i0);
    #pragma unroll
    for (int j = 0; j < 8; ++j) sum += b2f(xv[j]) * b2f(wv[j]);
  }
  #pragma unroll
  for (int m = 32; m >= 1; m >>= 1) sum += __shfl_xor(sum, m);
  if (lane == 0) gate[row] = 1.0f / (1.0f + __expf(-(sum + b2[0])));
}

// ------- V transpose + gate fold: [B,Sk,H,64] * g[B,Sk] -> [B*H,64,Sk] ------
__global__ __launch_bounds__(256) void vtrans_kernel(
    const bf16* __restrict__ V, const float* __restrict__ gate,
    bf16* __restrict__ VT, int Sk)
{
  __shared__ alignas(16) short tile[64][72];
  const int kt = blockIdx.x, h = blockIdx.y, b = blockIdx.z;
  const int tid = threadIdx.x;
  #pragma unroll
  for (int i = 0; i < 2; ++i) {
    const int c = tid + i * 256;        // 0..511
    const int kr = c >> 3, d0 = (c & 7) * 8;
    const float g = gate[(size_t)b * Sk + kt * 64 + kr];
    const s16x8 v = *(const s16x8*)(V + ((size_t)(b*Sk + kt*64 + kr)*NH + h)*HD + d0);
    #pragma unroll
    for (int j = 0; j < 8; ++j) tile[kr][d0 + j] = f2s(b2f(v[j]) * g);
  }
  __syncthreads();
  #pragma unroll
  for (int i = 0; i < 2; ++i) {
    const int c = tid + i * 256;
    const int d = c >> 3, k0 = (c & 7) * 8;
    s16x8 v;
    #pragma unroll
    for (int j = 0; j < 8; ++j) v[j] = tile[k0 + j][d];
    *(s16x8*)(VT + ((size_t)(b*NH + h)*HD + d)*Sk + kt*64 + k0) = v;
  }
}

// ---------------- fused dual-context flash attention -------------------------
// Swapped QK^T (mfma(K,Q)): lane owns ONE q-row (q=m16) -> scalar softmax
// state, 2+2 shfl reductions, P stays in-register for x16 PV MFMA.
// KVBLK=128, double-buffered global_load_lds staging, swizzled LDS.
__global__ __launch_bounds__(256) void attn_kernel(
    const bf16* __restrict__ Qh,   // [B][H][SQ][64], pre-scaled 0.125*log2e
    const bf16* __restrict__ K1h,  // [B][H][SKV][64]
    const bf16* __restrict__ VT1,  // [B*H][64][SKV] gated
    const bf16* __restrict__ K2h, const bf16* __restrict__ VT2,
    bf16* __restrict__ Hout)       // [B][SQ][H][64]
{
  __shared__ alignas(16) char sK[2][16384];   // 128 tok x 64 d, swizzled
  __shared__ alignas(16) char sVT[2][16384];  // 64 d x 128 k, swizzled
#if !HAVE_X16
  __shared__ alignas(16) char sP[4][4096];    // per-wave 16 q x 128 k
#endif
  const int tid = threadIdx.x, lane = tid & 63, wave = tid >> 6;
  const int hb = blockIdx.x;
  const int h = hb & 15, b = hb >> 4;
  const int q0 = blockIdx.y * 64 + wave * 16;
  const int m16 = lane & 15, g16 = lane >> 4;

  const bf16* qrow = Qh + ((size_t)(b*NH + h)*SQ + q0 + m16)*HD;
  const s16x8 qf0 = *(const s16x8*)(qrow + g16 * 8);
  const s16x8 qf1 = *(const s16x8*)(qrow + 32 + g16 * 8);

  const bf16* K1b  = K1h + (size_t)(b*NH + h) * SKV * HD;
  const bf16* K2b  = K2h + (size_t)(b*NH + h) * SKT * HD;
  const bf16* VT1b = VT1 + (size_t)(b*NH + h) * HD * SKV;
  const bf16* VT2b = VT2 + (size_t)(b*NH + h) * HD * SKT;

  auto stage = [&](const bf16* Kb, const bf16* VTb, int Sk, int kv0, int buf) {
    #pragma unroll
    for (int p = 0; p < 4; ++p) {
      const int idx = p * 256 + tid;
      const int kr = idx >> 3, kg = (idx & 7) ^ (kr & 7);
      gload16(Kb + (size_t)(kv0 + kr) * HD + kg * 8,
              &sK[buf][p * 4096 + wave * 1024]);
      const int vr = idx >> 4, vg = (idx & 15) ^ (vr & 7);
      gload16(VTb + (size_t)vr * Sk + kv0 + vg * 8,
              &sVT[buf][p * 4096 + wave * 1024]);
    }
  };

  float of[4][4];
  #pragma unroll
  for (int i = 0; i < 4; ++i)
    #pragma unroll
    for (int r = 0; r < 4; ++r) of[i][r] = 0.0f;

  f32x4 o[4];
  float mx, l;
  auto reset_state = [&]() {
    #pragma unroll
    for (int i = 0; i < 4; ++i)
      #pragma unroll
      for (int r = 0; r < 4; ++r) o[i][r] = 0.0f;
    mx = -1e30f; l = 0.0f;
  };
  auto flush_state = [&]() {
    float lv[4];
    #pragma unroll
    for (int r = 0; r < 4; ++r) lv[r] = __shfl(l, g16 * 4 + r);
    #pragma unroll
    for (int nd = 0; nd < 4; ++nd)
      #pragma unroll
      for (int r = 0; r < 4; ++r) of[nd][r] += o[nd][r] / lv[r];
  };

  auto chunk = [&](int buf) {
    // QK^T swapped: D[k][q], lane = (q=m16, k-group g16)
    f32x4 s[8];
    #pragma unroll
    for (int nt = 0; nt < 8; ++nt) {
      const char* kr = &sK[buf][(nt * 16 + m16) * 128];
      const s16x8 kf0 = *(const s16x8*)(kr + ((g16    ) ^ (m16 & 7)) * 16);
      const s16x8 kf1 = *(const s16x8*)(kr + ((4 + g16) ^ (m16 & 7)) * 16);
      f32x4 a2; a2[0] = 0; a2[1] = 0; a2[2] = 0; a2[3] = 0;
      a2 = MFMA32(kf0, qf0, a2);
      a2 = MFMA32(kf1, qf1, a2);
      s[nt] = a2;
    }
    // scalar online softmax for q=m16
    float mc = s[0][0];
    #pragma unroll
    for (int nt = 0; nt < 8; ++nt)
      #pragma unroll
      for (int r = 0; r < 4; ++r) mc = fmaxf(mc, s[nt][r]);
    mc = fmaxf(mc, __shfl_xor(mc, 16));
    mc = fmaxf(mc, __shfl_xor(mc, 32));
    const float mnew = fmaxf(mx, mc);
    const float alpha = exp2f(mx - mnew);
    mx = mnew;
    float p[8][4]; float rs = 0.0f;
    #pragma unroll
    for (int nt = 0; nt < 8; ++nt)
      #pragma unroll
      for (int r = 0; r < 4; ++r) { p[nt][r] = exp2f(s[nt][r] - mnew); rs += p[nt][r]; }
    rs += __shfl_xor(rs, 16);
    rs += __shfl_xor(rs, 32);
    l = l * alpha + rs;
    // redistribute alpha to PV row layout (q = g16*4+r)
    float av[4];
    #pragma unroll
    for (int r = 0; r < 4; ++r) av[r] = __shfl(alpha, g16 * 4 + r);
    #pragma unroll
    for (int nd = 0; nd < 4; ++nd)
      #pragma unroll
      for (int r = 0; r < 4; ++r) o[nd][r] *= av[r];
#if HAVE_X16
    // PV: in-register P fragments, 16x16x16 MFMA (k = g16*4+j in-lane)
    #pragma unroll
    for (int nt = 0; nt < 8; ++nt) {
      s16x4 pa;
      pa[0] = f2s(p[nt][0]); pa[1] = f2s(p[nt][1]);
      pa[2] = f2s(p[nt][2]); pa[3] = f2s(p[nt][3]);
      #pragma unroll
      for (int nd = 0; nd < 4; ++nd) {
        const int d = nd * 16 + m16;
        const int g = (2 * nt + (g16 >> 1)) ^ (d & 7);
        const s16x4 vf = *(const s16x4*)(&sVT[buf][d * 256 + g * 16 + (g16 & 1) * 8]);
        o[nd] = MFMA16(pa, vf, o[nd]);
      }
    }
#else
    // fallback: packed-b32 P through LDS, x32 PV
    #pragma unroll
    for (int nt = 0; nt < 8; ++nt) {
      const unsigned int w0 = pack2(p[nt][0], p[nt][1]);
      const unsigned int w1 = pack2(p[nt][2], p[nt][3]);
      const int g = (2 * nt + (g16 >> 1)) ^ (m16 & 7);
      char* basep = &sP[wave][m16 * 256 + g * 16 + (g16 & 1) * 8];
      *(unsigned int*)(basep) = w0;
      *(unsigned int*)(basep + 4) = w1;
    }
    #pragma unroll
    for (int ks = 0; ks < 4; ++ks) {
      const s16x8 pa = *(const s16x8*)(&sP[wave][m16 * 256 + ((ks * 4 + g16) ^ (m16 & 7)) * 16]);
      #pragma unroll
      for (int nd = 0; nd < 4; ++nd) {
        const int d = nd * 16 + m16;
        const s16x8 vf = *(const s16x8*)(&sVT[buf][d * 256 + ((ks * 4 + g16) ^ (d & 7)) * 16]);
        o[nd] = MFMA32(pa, vf, o[nd]);
      }
    }
#endif
  };

  stage(K1b, VT1b, SKV, 0, 0);
  __syncthreads();
  int cur = 0;

  reset_state();
  constexpr int NC1 = SKV / 128, NC2 = SKT / 128;
  for (int c = 0; c < NC1; ++c) {
    if (c + 1 < NC1) stage(K1b, VT1b, SKV, (c + 1) * 128, cur ^ 1);
    else             stage(K2b, VT2b, SKT, 0, cur ^ 1);
    chunk(cur);
    __syncthreads();
    cur ^= 1;
  }
  flush_state();

  reset_state();
  for (int c = 0; c < NC2; ++c) {
    if (c + 1 < NC2) stage(K2b, VT2b, SKT, (c + 1) * 128, cur ^ 1);
    chunk(cur);
    __syncthreads();
    cur ^= 1;
  }
  flush_state();

  #pragma unroll
  for (int nd = 0; nd < 4; ++nd)
    #pragma unroll
    for (int r = 0; r < 4; ++r) {
      const int row = q0 + g16 * 4 + r;
      Hout[((size_t)(b*SQ + row)*NH + h)*HD + nd*16 + m16] =
          __float2bfloat16(of[nd][r]);
    }
}

// ---------------- host launch ------------------------------------------------
extern "C" void kernel_launch(void* const* d_in, const int* in_sizes, int n_in,
                              void* d_out, int out_size, void* d_ws, size_t ws_size,
                              hipStream_t stream)
{
  const float* queries = (const float*)d_in[0];
  const float* ctx_v   = (const float*)d_in[1];
  const float* ctx_t   = (const float*)d_in[2];
  const float* w_nq = (const float*)d_in[3];
  const float* w_nv = (const float*)d_in[4];
  const float* w_nt = (const float*)d_in[5];
  const float* Wq   = (const float*)d_in[6];  const float* bq   = (const float*)d_in[7];
  const float* Wk_v = (const float*)d_in[8];  const float* bk_v = (const float*)d_in[9];
  const float* Wv_v = (const float*)d_in[10]; const float* bv_v = (const float*)d_in[11];
  const float* Wk_t = (const float*)d_in[12]; const float* bk_t = (const float*)d_in[13];
  const float* Wv_t = (const float*)d_in[14]; const float* bv_t = (const float*)d_in[15];
  const float* Wg1v = (const float*)d_in[16]; const float* bg1v = (const float*)d_in[17];
  const float* Wg2v = (const float*)d_in[18]; const float* bg2v = (const float*)d_in[19];
  const float* Wg1t = (const float*)d_in[20]; const float* bg1t = (const float*)d_in[21];
  const float* Wg2t = (const float*)d_in[22]; const float* bg2t = (const float*)d_in[23];
  const float* Wo   = (const float*)d_in[24]; const float* bo   = (const float*)d_in[25];

  char* ws = (char*)d_ws;
  size_t off = 0;
  auto alloc = [&](size_t n) { void* p = ws + off; off += (n + 255) & ~(size_t)255; return p; };

  const size_t MATB = (size_t)DIM * DIM * 2;
  bf16* WqB   = (bf16*)alloc(MATB);
  bf16* WkvB  = (bf16*)alloc(MATB);
  bf16* WvvB  = (bf16*)alloc(MATB);
  bf16* WktB  = (bf16*)alloc(MATB);
  bf16* WvtB  = (bf16*)alloc(MATB);
  bf16* Wg1vB = (bf16*)alloc(MATB);
  bf16* Wg1tB = (bf16*)alloc(MATB);
  bf16* WoB   = (bf16*)alloc(MATB);
  bf16* Wg2vB = (bf16*)alloc(2048);
  bf16* Wg2tB = (bf16*)alloc(2048);

  bf16* qn  = (bf16*)alloc((size_t)BB*SQ*DIM*2);
  bf16* cv  = (bf16*)alloc((size_t)BB*SKV*DIM*2);
  bf16* ct  = (bf16*)alloc((size_t)BB*SKT*DIM*2);
  bf16* qb  = (bf16*)alloc((size_t)BB*SQ*DIM*2);    // head-major, scaled
  bf16* kvB = (bf16*)alloc((size_t)BB*SKV*DIM*2);   // head-major
  bf16* ktB = (bf16*)alloc((size_t)BB*SKT*DIM*2);   // head-major
  bf16* vtV = (bf16*)alloc((size_t)BB*SKV*DIM*2);
  bf16* vtT = (bf16*)alloc((size_t)BB*SKT*DIM*2);
  bf16* vScr  = (bf16*)alloc((size_t)BB*SKV*DIM*2);   // reused vis then text
  bf16* g1Scr = (bf16*)alloc((size_t)BB*SKV*DIM*2);   // reused vis then text
  float* gateV = (float*)alloc((size_t)BB*SKV*4);
  float* gateT = (float*)alloc((size_t)BB*SKT*4);
  bf16* hB  = (bf16*)alloc((size_t)BB*SQ*DIM*2);
  (void)ws_size; (void)n_in; (void)in_sizes; (void)out_size;

  // 1. weight casts
  CastArgs ca;
  const float* wsrc[10] = {Wq, Wk_v, Wv_v, Wk_t, Wv_t, Wg1v, Wg1t, Wo, Wg2v, Wg2t};
  bf16* wdst[10] = {WqB, WkvB, WvvB, WktB, WvtB, Wg1vB, Wg1tB, WoB, Wg2vB, Wg2tB};
  for (int i = 0; i < 10; ++i) {
    ca.src[i] = wsrc[i]; ca.dst[i] = wdst[i];
    ca.n[i] = (i < 8) ? DIM * DIM : DIM;
  }
  cast_kernel<<<dim3(1024, 10), 256, 0, stream>>>(ca);

  // 2. RMSNorms
  NormArgs na;
  na.x[0] = queries; na.x[1] = ctx_v; na.x[2] = ctx_t;
  na.w[0] = w_nq;    na.w[1] = w_nv;  na.w[2] = w_nt;
  na.y[0] = qn;      na.y[1] = cv;    na.y[2] = ct;
  na.rows[0] = BB*SQ; na.rows[1] = BB*SKV; na.rows[2] = BB*SKT;
  rmsnorm_kernel<<<dim3(BB*SKV, 3), 256, 0, stream>>>(na);

  // 3. visual trio (K head-major, V, G1)
  GArgs gv{};
  gv.s[0] = {cv, WkvB,  bk_v, nullptr, kvB,   nullptr, 4, 11};
  gv.s[1] = {cv, WvvB,  bv_v, nullptr, vScr,  nullptr, 0, 0};
  gv.s[2] = {cv, Wg1vB, bg1v, nullptr, g1Scr, nullptr, 1, 0};
  gv.s[3] = gv.s[0];
  gemm_sb<<<dim3(BB*SKV/128, 8, 3), 256, 0, stream>>>(gv);
  gate_kernel<<<dim3(BB*SKV/4), 256, 0, stream>>>(g1Scr, Wg2vB, bg2v, gateV, BB*SKV);
  vtrans_kernel<<<dim3(SKV/64, NH, BB), 256, 0, stream>>>(vScr, gateV, vtV, SKV);

  // 4. Q (head-major, pre-scaled) + text trio
  GArgs gm{};
  gm.s[0] = {qn, WqB,   bq,   nullptr, qb,    nullptr, 3, 9};
  gm.s[1] = {ct, WktB,  bk_t, nullptr, ktB,   nullptr, 4, 9};
  gm.s[2] = {ct, WvtB,  bv_t, nullptr, vScr,  nullptr, 0, 0};
  gm.s[3] = {ct, Wg1tB, bg1t, nullptr, g1Scr, nullptr, 1, 0};
  gemm_sb<<<dim3(BB*SKT/128, 8, 4), 256, 0, stream>>>(gm);
  gate_kernel<<<dim3(BB*SKT/4), 256, 0, stream>>>(g1Scr, Wg2tB, bg2t, gateT, BB*SKT);
  vtrans_kernel<<<dim3(SKT/64, NH, BB), 256, 0, stream>>>(vScr, gateT, vtT, SKT);

  // 5. fused dual-context attention
  attn_kernel<<<dim3(NH*BB, SQ/64), 256, 0, stream>>>(qb, kvB, vtV, ktB, vtT, hB);

  // 6. output projection + residual (f32 out)
  GArgs go{};
  go.s[0] = {hB, WoB, bo, queries, nullptr, (float*)d_out, 2, 0};
  go.s[1] = go.s[0]; go.s[2] = go.s[0]; go.s[3] = go.s[0];
  gemm_sb<<<dim3(BB*SQ/128, 8, 1), 256, 0, stream>>>(go);
}

// Round 4
// 254.612 us; speedup vs baseline: 1.1297x; 1.1297x over previous
//
#include <hip/hip_runtime.h>
#include <hip/hip_bf16.h>

typedef __attribute__((ext_vector_type(4))) float f32x4;
typedef __attribute__((ext_vector_type(8))) short s16x8;
typedef __attribute__((ext_vector_type(4))) short s16x4;
using bf16 = __hip_bfloat16;

static constexpr int BB  = 4;
static constexpr int SQ  = 512;
static constexpr int SKV = 2048;
static constexpr int SKT = 512;
static constexpr int DIM = 1024;
static constexpr int NH  = 16;
static constexpr int HD  = 64;

#define MFMA32(A,B,C) __builtin_amdgcn_mfma_f32_16x16x32_bf16(A,B,C,0,0,0)

#if __has_builtin(__builtin_amdgcn_mfma_f32_16x16x16_bf16)
  #define MFMA16(A,B,C) __builtin_amdgcn_mfma_f32_16x16x16_bf16(A,B,C,0,0,0)
  #define HAVE_X16 1
#elif __has_builtin(__builtin_amdgcn_mfma_f32_16x16x16bf16_1k)
  #define MFMA16(A,B,C) __builtin_amdgcn_mfma_f32_16x16x16bf16_1k(A,B,C,0,0,0)
  #define HAVE_X16 1
#else
  #define HAVE_X16 0
#endif

__device__ __forceinline__ float b2f(short s) {
  unsigned int u = ((unsigned int)(unsigned short)s) << 16;
  float f; __builtin_memcpy(&f, &u, 4); return f;
}
__device__ __forceinline__ short f2s(float f) {
  bf16 h = __float2bfloat16(f); short s; __builtin_memcpy(&s, &h, 2); return s;
}

__device__ __forceinline__ void gload16(const void* g, void* l) {
  __builtin_amdgcn_global_load_lds(
      (const __attribute__((address_space(1))) void*)g,
      (__attribute__((address_space(3))) void*)l, 16, 0, 0);
}

// ---------------- weight cast f32 -> bf16 (batched via grid.y) --------------
struct CastArgs { const float* src[10]; bf16* dst[10]; int n[10]; };
__global__ __launch_bounds__(256) void cast_kernel(CastArgs a) {
  const int y = blockIdx.y;
  const int n = a.n[y];
  const int i = (blockIdx.x * 256 + threadIdx.x) * 4;
  if (i >= n) return;
  const float4 v = *(const float4*)(a.src[y] + i);
  bf16* d = a.dst[y] + i;
  d[0] = __float2bfloat16(v.x); d[1] = __float2bfloat16(v.y);
  d[2] = __float2bfloat16(v.z); d[3] = __float2bfloat16(v.w);
}

// ---------------- RMSNorm (f32 in, bf16 out), one block per row -------------
struct NormArgs { const float* x[3]; const float* w[3]; bf16* y[3]; int rows[3]; };
__global__ __launch_bounds__(256) void rmsnorm_kernel(NormArgs a) {
  const int t = blockIdx.y, row = blockIdx.x;
  if (row >= a.rows[t]) return;
  const float* x = a.x[t] + (size_t)row * DIM;
  const float4 v = *(const float4*)(x + threadIdx.x * 4);
  float ss = v.x*v.x + v.y*v.y + v.z*v.z + v.w*v.w;
  #pragma unroll
  for (int m = 32; m >= 1; m >>= 1) ss += __shfl_xor(ss, m);
  __shared__ float red[4];
  if ((threadIdx.x & 63) == 0) red[threadIdx.x >> 6] = ss;
  __syncthreads();
  ss = red[0] + red[1] + red[2] + red[3];
  const float sc = rsqrtf(ss * (1.0f / DIM) + 1.1920928955078125e-07f);
  const float4 w = *(const float4*)(a.w[t] + threadIdx.x * 4);
  bf16* y = a.y[t] + (size_t)row * DIM + threadIdx.x * 4;
  y[0] = __float2bfloat16(v.x * sc * w.x);
  y[1] = __float2bfloat16(v.y * sc * w.y);
  y[2] = __float2bfloat16(v.z * sc * w.z);
  y[3] = __float2bfloat16(v.w * sc * w.w);
}

// ---------------- GEMM: C = act(A @ W^T + bias), slot-batched ----------------
// m97 structure: 128x128 tile, BK=32, single-buffered 16 KB LDS,
// stage -> barrier -> 16 MFMA -> barrier. 16B-granule XOR swizzle both sides.
struct GSlot { const bf16* A; const bf16* W; const float* bias;
               const float* resid; bf16* Cb; float* Cf; int epi; int sksh; };
struct GArgs { GSlot s[4]; };

static constexpr float QSCALE = 0.180336880111120426f;  // 0.125 * log2(e)

__global__ __launch_bounds__(256) void gemm_sb(GArgs a) {
  constexpr int K = DIM;
  __shared__ alignas(16) char sA[8192];
  __shared__ alignas(16) char sB[8192];
  const GSlot S = a.s[blockIdx.z];
  const int tid = threadIdx.x, lane = tid & 63, wave = tid >> 6;
  const int bm = blockIdx.x, bn = blockIdx.y;
  const int wm = wave >> 1, wn = wave & 1;
  const int m16 = lane & 15, g16 = lane >> 4;

  f32x4 acc[4][4];
  #pragma unroll
  for (int i = 0; i < 4; ++i)
    #pragma unroll
    for (int j = 0; j < 4; ++j)
      #pragma unroll
      for (int r = 0; r < 4; ++r) acc[i][j][r] = 0.0f;

  const bf16* Ab = S.A + (size_t)bm * 128 * K;
  const bf16* Wb = S.W + (size_t)bn * 128 * K;

  for (int t = 0; t < K / 32; ++t) {
    const int k0 = t * 32;
    #pragma unroll
    for (int p = 0; p < 2; ++p) {
      const int idx = p * 256 + tid;
      const int row = idx >> 2, sg = (idx & 3) ^ (row & 3);
      const size_t so = (size_t)row * K + k0 + sg * 8;
      gload16(Ab + so, &sA[p * 4096 + wave * 1024]);
      gload16(Wb + so, &sB[p * 4096 + wave * 1024]);
    }
    __syncthreads();
    s16x8 af[4], bfr[4];
    #pragma unroll
    for (int mi = 0; mi < 4; ++mi) {
      const int row = wm * 64 + mi * 16 + m16;
      af[mi] = *(const s16x8*)(&sA[row * 64 + (g16 ^ (m16 & 3)) * 16]);
    }
    #pragma unroll
    for (int ni = 0; ni < 4; ++ni) {
      const int row = wn * 64 + ni * 16 + m16;
      bfr[ni] = *(const s16x8*)(&sB[row * 64 + (g16 ^ (m16 & 3)) * 16]);
    }
    #pragma unroll
    for (int mi = 0; mi < 4; ++mi)
      #pragma unroll
      for (int ni = 0; ni < 4; ++ni)
        acc[mi][ni] = MFMA32(af[mi], bfr[ni], acc[mi][ni]);
    __syncthreads();
  }

  const int r0 = bm * 128 + wm * 64, c0 = bn * 128 + wn * 64;
  if (S.epi >= 3) {
    const float sc = (S.epi == 3) ? QSCALE : 1.0f;
    const int msk = (1 << S.sksh) - 1;
    #pragma unroll
    for (int ni = 0; ni < 4; ++ni) {
      const int col = c0 + ni * 16 + m16;
      const int hh = col >> 6, d = col & 63;
      const float bv = S.bias[col];
      #pragma unroll
      for (int mi = 0; mi < 4; ++mi) {
        const int rowb = r0 + mi * 16 + g16 * 4;
        #pragma unroll
        for (int r = 0; r < 4; ++r) {
          const int m = rowb + r;
          const int bb2 = m >> S.sksh, tok = m & msk;
          S.Cb[(((size_t)(bb2 * NH + hh) << S.sksh) + tok) * HD + d] =
              __float2bfloat16((acc[mi][ni][r] + bv) * sc);
        }
      }
    }
  } else {
    #pragma unroll
    for (int ni = 0; ni < 4; ++ni) {
      const int col = c0 + ni * 16 + m16;
      const float bv = S.bias[col];
      #pragma unroll
      for (int mi = 0; mi < 4; ++mi) {
        const int rowb = r0 + mi * 16 + g16 * 4;
        #pragma unroll
        for (int r = 0; r < 4; ++r) {
          float v = acc[mi][ni][r] + bv;
          const size_t idx = (size_t)(rowb + r) * DIM + col;
          if (S.epi == 1)      { v = v / (1.0f + __expf(-v)); S.Cb[idx] = __float2bfloat16(v); }
          else if (S.epi == 2) { S.Cf[idx] = v + S.resid[idx]; }
          else                 { S.Cb[idx] = __float2bfloat16(v); }
        }
      }
    }
  }
}

// ---------------- gate GEMV: gate = sigmoid(g1 . w2 + b2), wave per row -----
__global__ __launch_bounds__(256) void gate_kernel(
    const bf16* __restrict__ g1, const bf16* __restrict__ w2,
    const float* __restrict__ b2, float* __restrict__ gate, int rows)
{
  const int lane = threadIdx.x & 63, wave = threadIdx.x >> 6;
  const int row = blockIdx.x * 4 + wave;
  if (row >= rows) return;
  const bf16* x = g1 + (size_t)row * DIM;
  float sum = 0.0f;
  #pragma unroll
  for (int c = 0; c < 2; ++c) {
    const int i0 = c * 512 + lane * 8;
    const s16x8 xv = *(const s16x8*)(x + i0);
    const s16x8 wv = *(const s16x8*)(w2 + i0);
    #pragma unroll
    for (int j = 0; j < 8; ++j) sum += b2f(xv[j]) * b2f(wv[j]);
  }
  #pragma unroll
  for (int m = 32; m >= 1; m >>= 1) sum += __shfl_xor(sum, m);
  if (lane == 0) gate[row] = 1.0f / (1.0f + __expf(-(sum + b2[0])));
}

// ------- V transpose + gate fold: [B,Sk,H,64] * g[B,Sk] -> [B*H,64,Sk] ------
__global__ __launch_bounds__(256) void vtrans_kernel(
    const bf16* __restrict__ V, const float* __restrict__ gate,
    bf16* __restrict__ VT, int Sk)
{
  __shared__ alignas(16) short tile[64][72];
  const int kt = blockIdx.x, h = blockIdx.y, b = blockIdx.z;
  const int tid = threadIdx.x;
  #pragma unroll
  for (int i = 0; i < 2; ++i) {
    const int c = tid + i * 256;        // 0..511
    const int kr = c >> 3, d0 = (c & 7) * 8;
    const float g = gate[(size_t)b * Sk + kt * 64 + kr];
    const s16x8 v = *(const s16x8*)(V + ((size_t)(b*Sk + kt*64 + kr)*NH + h)*HD + d0);
    #pragma unroll
    for (int j = 0; j < 8; ++j) tile[kr][d0 + j] = f2s(b2f(v[j]) * g);
  }
  __syncthreads();
  #pragma unroll
  for (int i = 0; i < 2; ++i) {
    const int c = tid + i * 256;
    const int d = c >> 3, k0 = (c & 7) * 8;
    s16x8 v;
    #pragma unroll
    for (int j = 0; j < 8; ++j) v[j] = tile[k0 + j][d];
    *(s16x8*)(VT + ((size_t)(b*NH + h)*HD + d)*Sk + kt*64 + k0) = v;
  }
}

// ---------------- fused dual-context flash attention -------------------------
// 1024 blocks (bh fast axis x 16 q-tiles of 32 rows), 4 waves @ 32 KB LDS
// -> 4 blocks/CU, 16 waves/CU. Waves {0,1}: kv-half 0; {2,3}: kv-half 1;
// block-local online-softmax merge through LDS at each context end.
// Swapped QK^T (mfma(K,Q)): scalar softmax state, P stays in-register.
__global__ __launch_bounds__(256, 4) void attn_kernel(
    const bf16* __restrict__ Qh,   // [B][H][SQ][64], pre-scaled 0.125*log2e
    const bf16* __restrict__ K1h,  // [B][H][SKV][64]
    const bf16* __restrict__ VT1,  // [B*H][64][SKV] gated
    const bf16* __restrict__ K2h, const bf16* __restrict__ VT2,
    bf16* __restrict__ Hout)       // [B][SQ][H][64]
{
  __shared__ alignas(16) char sK[2][8192];   // [kv-half][64 tok x 64 d]
  __shared__ alignas(16) char sVT[2][8192];  // [kv-half][64 d x 64 kv]
  const int tid = threadIdx.x, lane = tid & 63, wave = tid >> 6;
  const int hb = blockIdx.x;
  const int h = hb & 15, b = hb >> 4;
  const int wq = wave & 1, hf = wave >> 1;
  const int q0 = blockIdx.y * 32 + wq * 16;
  const int m16 = lane & 15, g16 = lane >> 4;

  const bf16* qrow = Qh + ((size_t)(b*NH + h)*SQ + q0 + m16)*HD;
  const s16x8 qf0 = *(const s16x8*)(qrow + g16 * 8);
  const s16x8 qf1 = *(const s16x8*)(qrow + 32 + g16 * 8);

  const bf16* K1b  = K1h + (size_t)(b*NH + h) * SKV * HD;
  const bf16* K2b  = K2h + (size_t)(b*NH + h) * SKT * HD;
  const bf16* VT1b = VT1 + (size_t)(b*NH + h) * HD * SKV;
  const bf16* VT2b = VT2 + (size_t)(b*NH + h) * HD * SKT;

  // stage both kv-halves' 64-chunk (K 2x8KB + VT 2x8KB), pre-swizzled source
  auto stage = [&](const bf16* Kb, const bf16* VTb, int Sk, int b0, int b1) {
    #pragma unroll
    for (int p = 0; p < 2; ++p) {
      const int idx = p * 256 + tid;
      const int r = idx >> 3, g = (idx & 7) ^ (r & 7);
      char* dst = (char*)nullptr;
      gload16(Kb  + (size_t)(b0 + r) * HD + g * 8, &sK[0][p * 4096 + wave * 1024]);
      gload16(Kb  + (size_t)(b1 + r) * HD + g * 8, &sK[1][p * 4096 + wave * 1024]);
      gload16(VTb + (size_t)r * Sk + b0 + g * 8,   &sVT[0][p * 4096 + wave * 1024]);
      gload16(VTb + (size_t)r * Sk + b1 + g * 8,   &sVT[1][p * 4096 + wave * 1024]);
      (void)dst;
    }
  };

  float of[4][4];
  #pragma unroll
  for (int i = 0; i < 4; ++i)
    #pragma unroll
    for (int r = 0; r < 4; ++r) of[i][r] = 0.0f;

  f32x4 o[4];
  float mx, l;
  auto reset_state = [&]() {
    #pragma unroll
    for (int i = 0; i < 4; ++i)
      #pragma unroll
      for (int r = 0; r < 4; ++r) o[i][r] = 0.0f;
    mx = -1e30f; l = 0.0f;
  };

  auto chunk = [&]() {
    const char* kbase = &sK[hf][0];
    const char* vbase = &sVT[hf][0];
    // QK^T swapped: D[k][q]; lane = (q=m16, k-group g16)
    f32x4 s[4];
    #pragma unroll
    for (int nt = 0; nt < 4; ++nt) {
      const char* kr = kbase + (nt * 16 + m16) * 128;
      const s16x8 kf0 = *(const s16x8*)(kr + ((g16    ) ^ (m16 & 7)) * 16);
      const s16x8 kf1 = *(const s16x8*)(kr + ((4 + g16) ^ (m16 & 7)) * 16);
      f32x4 a2; a2[0] = 0; a2[1] = 0; a2[2] = 0; a2[3] = 0;
      a2 = MFMA32(kf0, qf0, a2);
      a2 = MFMA32(kf1, qf1, a2);
      s[nt] = a2;
    }
    // scalar online softmax for q = m16 (exp2 domain)
    float mc = s[0][0];
    #pragma unroll
    for (int nt = 0; nt < 4; ++nt)
      #pragma unroll
      for (int r = 0; r < 4; ++r) mc = fmaxf(mc, s[nt][r]);
    mc = fmaxf(mc, __shfl_xor(mc, 16));
    mc = fmaxf(mc, __shfl_xor(mc, 32));
    const float mnew = fmaxf(mx, mc);
    const float alpha = exp2f(mx - mnew);
    mx = mnew;
    float p[4][4]; float rs = 0.0f;
    #pragma unroll
    for (int nt = 0; nt < 4; ++nt)
      #pragma unroll
      for (int r = 0; r < 4; ++r) { p[nt][r] = exp2f(s[nt][r] - mnew); rs += p[nt][r]; }
    rs += __shfl_xor(rs, 16);
    rs += __shfl_xor(rs, 32);
    l = l * alpha + rs;
    float av[4];
    #pragma unroll
    for (int r = 0; r < 4; ++r) av[r] = __shfl(alpha, g16 * 4 + r);
    #pragma unroll
    for (int nd = 0; nd < 4; ++nd)
      #pragma unroll
      for (int r = 0; r < 4; ++r) o[nd][r] *= av[r];
#if HAVE_X16
    #pragma unroll
    for (int nt = 0; nt < 4; ++nt) {
      s16x4 pa;
      pa[0] = f2s(p[nt][0]); pa[1] = f2s(p[nt][1]);
      pa[2] = f2s(p[nt][2]); pa[3] = f2s(p[nt][3]);
      #pragma unroll
      for (int nd = 0; nd < 4; ++nd) {
        const int d = nd * 16 + m16;
        const int g = (nt * 2 + (g16 >> 1)) ^ (m16 & 7);
        const s16x4 vf = *(const s16x4*)(vbase + d * 128 + g * 16 + (g16 & 1) * 8);
        o[nd] = MFMA16(pa, vf, o[nd]);
      }
    }
#else
    // fallback: pack pairs of k into s16x8 via shfl from partner k-groups
    #pragma unroll
    for (int nt = 0; nt < 2; ++nt) {
      s16x8 pa;
      #pragma unroll
      for (int j = 0; j < 8; ++j) pa[j] = 0;  // placeholder; HAVE_X16 expected
      (void)pa;
    }
#endif
  };

  // merge partner kv-half state into of (hf==0 owns output)
  auto merge_flush = [&]() {
    __syncthreads();
    float* mo = (float*)&sK[0][0];    // [2][16][64] f32 = 8 KB
    float* ml = (float*)&sVT[0][0];   // [2][2][16]  f32
    if (hf) {
      #pragma unroll
      for (int nd = 0; nd < 4; ++nd)
        #pragma unroll
        for (int r = 0; r < 4; ++r)
          mo[(wq * 16 + g16 * 4 + r) * 64 + nd * 16 + m16] = o[nd][r];
      if (g16 == 0) { ml[(wq * 2 + 0) * 16 + m16] = mx; ml[(wq * 2 + 1) * 16 + m16] = l; }
    }
    __syncthreads();
    if (!hf) {
      const float mb = ml[(wq * 2 + 0) * 16 + m16];
      const float lb = ml[(wq * 2 + 1) * 16 + m16];
      const float ms = fmaxf(mx, mb);
      const float aA = exp2f(mx - ms), aB = exp2f(mb - ms);
      const float lt = l * aA + lb * aB;
      float aAv[4], aBv[4], ltv[4];
      #pragma unroll
      for (int r = 0; r < 4; ++r) {
        aAv[r] = __shfl(aA, g16 * 4 + r);
        aBv[r] = __shfl(aB, g16 * 4 + r);
        ltv[r] = __shfl(lt, g16 * 4 + r);
      }
      #pragma unroll
      for (int nd = 0; nd < 4; ++nd)
        #pragma unroll
        for (int r = 0; r < 4; ++r) {
          const float ob = mo[(wq * 16 + g16 * 4 + r) * 64 + nd * 16 + m16];
          of[nd][r] += (o[nd][r] * aAv[r] + ob * aBv[r]) / ltv[r];
        }
    }
    __syncthreads();
  };

  reset_state();
  for (int c = 0; c < SKV / 128; ++c) {      // 16 chunks of 64 per half
    stage(K1b, VT1b, SKV, c * 64, 1024 + c * 64);
    __syncthreads();
    chunk();
    __syncthreads();
  }
  merge_flush();

  reset_state();
  for (int c = 0; c < SKT / 128; ++c) {      // 4 chunks of 64 per half
    stage(K2b, VT2b, SKT, c * 64, 256 + c * 64);
    __syncthreads();
    chunk();
    __syncthreads();
  }
  merge_flush();

  if (!hf) {
    #pragma unroll
    for (int nd = 0; nd < 4; ++nd)
      #pragma unroll
      for (int r = 0; r < 4; ++r) {
        const int row = q0 + g16 * 4 + r;
        Hout[((size_t)(b*SQ + row)*NH + h)*HD + nd*16 + m16] =
            __float2bfloat16(of[nd][r]);
      }
  }
}

// ---------------- host launch ------------------------------------------------
extern "C" void kernel_launch(void* const* d_in, const int* in_sizes, int n_in,
                              void* d_out, int out_size, void* d_ws, size_t ws_size,
                              hipStream_t stream)
{
  const float* queries = (const float*)d_in[0];
  const float* ctx_v   = (const float*)d_in[1];
  const float* ctx_t   = (const float*)d_in[2];
  const float* w_nq = (const float*)d_in[3];
  const float* w_nv = (const float*)d_in[4];
  const float* w_nt = (const float*)d_in[5];
  const float* Wq   = (const float*)d_in[6];  const float* bq   = (const float*)d_in[7];
  const float* Wk_v = (const float*)d_in[8];  const float* bk_v = (const float*)d_in[9];
  const float* Wv_v = (const float*)d_in[10]; const float* bv_v = (const float*)d_in[11];
  const float* Wk_t = (const float*)d_in[12]; const float* bk_t = (const float*)d_in[13];
  const float* Wv_t = (const float*)d_in[14]; const float* bv_t = (const float*)d_in[15];
  const float* Wg1v = (const float*)d_in[16]; const float* bg1v = (const float*)d_in[17];
  const float* Wg2v = (const float*)d_in[18]; const float* bg2v = (const float*)d_in[19];
  const float* Wg1t = (const float*)d_in[20]; const float* bg1t = (const float*)d_in[21];
  const float* Wg2t = (const float*)d_in[22]; const float* bg2t = (const float*)d_in[23];
  const float* Wo   = (const float*)d_in[24]; const float* bo   = (const float*)d_in[25];

  char* ws = (char*)d_ws;
  size_t off = 0;
  auto alloc = [&](size_t n) { void* p = ws + off; off += (n + 255) & ~(size_t)255; return p; };

  const size_t MATB = (size_t)DIM * DIM * 2;
  bf16* WqB   = (bf16*)alloc(MATB);
  bf16* WkvB  = (bf16*)alloc(MATB);
  bf16* WvvB  = (bf16*)alloc(MATB);
  bf16* WktB  = (bf16*)alloc(MATB);
  bf16* WvtB  = (bf16*)alloc(MATB);
  bf16* Wg1vB = (bf16*)alloc(MATB);
  bf16* Wg1tB = (bf16*)alloc(MATB);
  bf16* WoB   = (bf16*)alloc(MATB);
  bf16* Wg2vB = (bf16*)alloc(2048);
  bf16* Wg2tB = (bf16*)alloc(2048);

  bf16* qn  = (bf16*)alloc((size_t)BB*SQ*DIM*2);
  bf16* cv  = (bf16*)alloc((size_t)BB*SKV*DIM*2);
  bf16* ct  = (bf16*)alloc((size_t)BB*SKT*DIM*2);
  bf16* qb  = (bf16*)alloc((size_t)BB*SQ*DIM*2);    // head-major, scaled
  bf16* kvB = (bf16*)alloc((size_t)BB*SKV*DIM*2);   // head-major
  bf16* ktB = (bf16*)alloc((size_t)BB*SKT*DIM*2);   // head-major
  bf16* vtV = (bf16*)alloc((size_t)BB*SKV*DIM*2);
  bf16* vtT = (bf16*)alloc((size_t)BB*SKT*DIM*2);
  bf16* vScr  = (bf16*)alloc((size_t)BB*SKV*DIM*2);   // reused vis then text
  bf16* g1Scr = (bf16*)alloc((size_t)BB*SKV*DIM*2);   // reused vis then text
  float* gateV = (float*)alloc((size_t)BB*SKV*4);
  float* gateT = (float*)alloc((size_t)BB*SKT*4);
  bf16* hB  = (bf16*)alloc((size_t)BB*SQ*DIM*2);
  (void)ws_size; (void)n_in; (void)in_sizes; (void)out_size;

  // 1. weight casts
  CastArgs ca;
  const float* wsrc[10] = {Wq, Wk_v, Wv_v, Wk_t, Wv_t, Wg1v, Wg1t, Wo, Wg2v, Wg2t};
  bf16* wdst[10] = {WqB, WkvB, WvvB, WktB, WvtB, Wg1vB, Wg1tB, WoB, Wg2vB, Wg2tB};
  for (int i = 0; i < 10; ++i) {
    ca.src[i] = wsrc[i]; ca.dst[i] = wdst[i];
    ca.n[i] = (i < 8) ? DIM * DIM : DIM;
  }
  cast_kernel<<<dim3(1024, 10), 256, 0, stream>>>(ca);

  // 2. RMSNorms
  NormArgs na;
  na.x[0] = queries; na.x[1] = ctx_v; na.x[2] = ctx_t;
  na.w[0] = w_nq;    na.w[1] = w_nv;  na.w[2] = w_nt;
  na.y[0] = qn;      na.y[1] = cv;    na.y[2] = ct;
  na.rows[0] = BB*SQ; na.rows[1] = BB*SKV; na.rows[2] = BB*SKT;
  rmsnorm_kernel<<<dim3(BB*SKV, 3), 256, 0, stream>>>(na);

  // 3. visual trio (K head-major, V, G1)
  GArgs gv{};
  gv.s[0] = {cv, WkvB,  bk_v, nullptr, kvB,   nullptr, 4, 11};
  gv.s[1] = {cv, WvvB,  bv_v, nullptr, vScr,  nullptr, 0, 0};
  gv.s[2] = {cv, Wg1vB, bg1v, nullptr, g1Scr, nullptr, 1, 0};
  gv.s[3] = gv.s[0];
  gemm_sb<<<dim3(BB*SKV/128, 8, 3), 256, 0, stream>>>(gv);
  gate_kernel<<<dim3(BB*SKV/4), 256, 0, stream>>>(g1Scr, Wg2vB, bg2v, gateV, BB*SKV);
  vtrans_kernel<<<dim3(SKV/64, NH, BB), 256, 0, stream>>>(vScr, gateV, vtV, SKV);

  // 4. Q (head-major, pre-scaled) + text trio
  GArgs gm{};
  gm.s[0] = {qn, WqB,   bq,   nullptr, qb,    nullptr, 3, 9};
  gm.s[1] = {ct, WktB,  bk_t, nullptr, ktB,   nullptr, 4, 9};
  gm.s[2] = {ct, WvtB,  bv_t, nullptr, vScr,  nullptr, 0, 0};
  gm.s[3] = {ct, Wg1tB, bg1t, nullptr, g1Scr, nullptr, 1, 0};
  gemm_sb<<<dim3(BB*SKT/128, 8, 4), 256, 0, stream>>>(gm);
  gate_kernel<<<dim3(BB*SKT/4), 256, 0, stream>>>(g1Scr, Wg2tB, bg2t, gateT, BB*SKT);
  vtrans_kernel<<<dim3(SKT/64, NH, BB), 256, 0, stream>>>(vScr, gateT, vtT, SKT);

  // 5. fused dual-context attention (1024 blocks, kv-split across wave pairs)
  attn_kernel<<<dim3(NH*BB, SQ/32), 256, 0, stream>>>(qb, kvB, vtV, ktB, vtT, hB);

  // 6. output projection + residual (f32 out)
  GArgs go{};
  go.s[0] = {hB, WoB, bo, queries, nullptr, (float*)d_out, 2, 0};
  go.s[1] = go.s[0]; go.s[2] = go.s[0]; go.s[3] = go.s[0];
  gemm_sb<<<dim3(BB*SQ/128, 8, 1), 256, 0, stream>>>(go);
}

// Round 5
// 214.023 us; speedup vs baseline: 1.3440x; 1.1896x over previous
//
#include <hip/hip_runtime.h>
#include <hip/hip_bf16.h>

typedef __attribute__((ext_vector_type(4))) float f32x4;
typedef __attribute__((ext_vector_type(8))) short s16x8;
typedef __attribute__((ext_vector_type(4))) short s16x4;
using bf16 = __hip_bfloat16;

static constexpr int BB  = 4;
static constexpr int SQ  = 512;
static constexpr int SKV = 2048;
static constexpr int SKT = 512;
static constexpr int DIM = 1024;
static constexpr int NH  = 16;
static constexpr int HD  = 64;

#define MFMA32(A,B,C) __builtin_amdgcn_mfma_f32_16x16x32_bf16(A,B,C,0,0,0)

#if __has_builtin(__builtin_amdgcn_mfma_f32_16x16x16_bf16)
  #define MFMA16(A,B,C) __builtin_amdgcn_mfma_f32_16x16x16_bf16(A,B,C,0,0,0)
  #define HAVE_X16 1
#elif __has_builtin(__builtin_amdgcn_mfma_f32_16x16x16bf16_1k)
  #define MFMA16(A,B,C) __builtin_amdgcn_mfma_f32_16x16x16bf16_1k(A,B,C,0,0,0)
  #define HAVE_X16 1
#else
  #define HAVE_X16 0
#endif

#define SBAR() asm volatile("s_barrier" ::: "memory")

__device__ __forceinline__ float b2f(short s) {
  unsigned int u = ((unsigned int)(unsigned short)s) << 16;
  float f; __builtin_memcpy(&f, &u, 4); return f;
}
__device__ __forceinline__ short f2s(float f) {
  bf16 h = __float2bfloat16(f); short s; __builtin_memcpy(&s, &h, 2); return s;
}

__device__ __forceinline__ void gload16(const void* g, void* l) {
  __builtin_amdgcn_global_load_lds(
      (const __attribute__((address_space(1))) void*)g,
      (__attribute__((address_space(3))) void*)l, 16, 0, 0);
}

static constexpr float QSCALE = 0.180336880111120426f;  // 0.125 * log2(e)

// ---------------- weight cast f32 -> bf16 (batched via grid.y) --------------
struct CastArgs { const float* src[10]; bf16* dst[10]; int n[10]; };
__global__ __launch_bounds__(256) void cast_kernel(CastArgs a) {
  const int y = blockIdx.y;
  const int n = a.n[y];
  const int i = (blockIdx.x * 256 + threadIdx.x) * 4;
  if (i >= n) return;
  const float4 v = *(const float4*)(a.src[y] + i);
  bf16* d = a.dst[y] + i;
  d[0] = __float2bfloat16(v.x); d[1] = __float2bfloat16(v.y);
  d[2] = __float2bfloat16(v.z); d[3] = __float2bfloat16(v.w);
}

// ---------------- RMSNorm (f32 in, bf16 out), one block per row -------------
struct NormArgs { const float* x[3]; const float* w[3]; bf16* y[3]; int rows[3]; };
__global__ __launch_bounds__(256) void rmsnorm_kernel(NormArgs a) {
  const int t = blockIdx.y, row = blockIdx.x;
  if (row >= a.rows[t]) return;
  const float* x = a.x[t] + (size_t)row * DIM;
  const float4 v = *(const float4*)(x + threadIdx.x * 4);
  float ss = v.x*v.x + v.y*v.y + v.z*v.z + v.w*v.w;
  #pragma unroll
  for (int m = 32; m >= 1; m >>= 1) ss += __shfl_xor(ss, m);
  __shared__ float red[4];
  if ((threadIdx.x & 63) == 0) red[threadIdx.x >> 6] = ss;
  __syncthreads();
  ss = red[0] + red[1] + red[2] + red[3];
  const float sc = rsqrtf(ss * (1.0f / DIM) + 1.1920928955078125e-07f);
  const float4 w = *(const float4*)(a.w[t] + threadIdx.x * 4);
  bf16* y = a.y[t] + (size_t)row * DIM + threadIdx.x * 4;
  y[0] = __float2bfloat16(v.x * sc * w.x);
  y[1] = __float2bfloat16(v.y * sc * w.y);
  y[2] = __float2bfloat16(v.z * sc * w.z);
  y[3] = __float2bfloat16(v.w * sc * w.w);
}

// ============== 256x256 8-wave pipelined projection GEMM =====================
// BK=64, K-tile double-buffer (128 KB LDS), 4 interleaved phases per K-tile,
// global_load_lds direct staging (linear dest + g^(row&7) pre-swizzled source),
// raw s_barrier + one vmcnt(0) wait per K-tile (loads fly 2-3 phases),
// setprio around MFMA clusters. 7 slots flat-decoded, XCD-bijective swizzle.
struct PSlot { const bf16* A; const bf16* W; const float* bias;
               bf16* Cb; int epi; int sksh; };
struct PArgs { PSlot s[7]; };

__global__ __launch_bounds__(512, 2) void proj256(PArgs a) {
  __shared__ char lds[131072];   // [buf][A 32KB | B 32KB]
  const int tid = threadIdx.x, lane = tid & 63, wave = tid >> 6;
  const int m16 = lane & 15, g16 = lane >> 4;
  const int wm = wave >> 2, wn = wave & 3;

  // XCD-bijective swizzle (512 % 8 == 0) + slot decode (bn fastest)
  const int i = (blockIdx.x & 7) * 64 + (blockIdx.x >> 3);
  int slot, rem;
  if (i < 384) { slot = i >> 7; rem = i & 127; }
  else { const int j = i - 384; slot = 3 + (j >> 5); rem = j & 31; }
  const PSlot S = a.s[slot];
  const int bn = rem & 3, bm = rem >> 2;

  const bf16* Ab = S.A + (size_t)bm * 256 * DIM;
  const bf16* Wb = S.W + (size_t)bn * 256 * DIM;

  auto stageA = [&](int k0, int buf) {
    #pragma unroll
    for (int q = 0; q < 4; ++q) {
      const int idx = q * 512 + tid;
      const int row = idx >> 3, g = (idx & 7) ^ (row & 7);
      gload16(Ab + (size_t)row * DIM + k0 + g * 8,
              &lds[buf * 65536 + q * 8192 + wave * 1024]);
    }
  };
  auto stageB = [&](int k0, int buf) {
    #pragma unroll
    for (int q = 0; q < 4; ++q) {
      const int idx = q * 512 + tid;
      const int row = idx >> 3, g = (idx & 7) ^ (row & 7);
      gload16(Wb + (size_t)row * DIM + k0 + g * 8,
              &lds[buf * 65536 + 32768 + q * 8192 + wave * 1024]);
    }
  };

  f32x4 acc[8][4];
  #pragma unroll
  for (int x = 0; x < 8; ++x)
    #pragma unroll
    for (int y = 0; y < 4; ++y)
      #pragma unroll
      for (int r = 0; r < 4; ++r) acc[x][y][r] = 0.0f;

  stageA(0, 0); stageB(0, 0);
  asm volatile("s_waitcnt vmcnt(0)" ::: "memory");
  SBAR();

  for (int t = 0; t < DIM / 64; ++t) {
    const int buf = t & 1;
    const char* A0 = &lds[buf * 65536];
    const char* B0 = A0 + 32768;
    s16x8 af[4][2], bf0[2][2], bf1[2][2];

    // ---- phase 0: dsA(m-half0) 8 + dsB(n-half0) 4; stage A(t+1) ----
    #pragma unroll
    for (int mi = 0; mi < 4; ++mi) {
      const int row = wm * 128 + mi * 16 + m16;
      #pragma unroll
      for (int ks = 0; ks < 2; ++ks)
        af[mi][ks] = *(const s16x8*)(A0 + row * 128 + (((ks*4+g16) ^ (m16 & 7)) * 16));
    }
    #pragma unroll
    for (int ni = 0; ni < 2; ++ni) {
      const int row = wn * 64 + ni * 16 + m16;
      #pragma unroll
      for (int ks = 0; ks < 2; ++ks)
        bf0[ni][ks] = *(const s16x8*)(B0 + row * 128 + (((ks*4+g16) ^ (m16 & 7)) * 16));
    }
    if (t + 1 < DIM / 64) stageA((t + 1) * 64, buf ^ 1);
    SBAR();
    __builtin_amdgcn_s_setprio(1);
    #pragma unroll
    for (int mi = 0; mi < 4; ++mi)
      #pragma unroll
      for (int ni = 0; ni < 2; ++ni) {
        acc[mi][ni] = MFMA32(af[mi][0], bf0[ni][0], acc[mi][ni]);
        acc[mi][ni] = MFMA32(af[mi][1], bf0[ni][1], acc[mi][ni]);
      }
    __builtin_amdgcn_s_setprio(0);
    SBAR();

    // ---- phase 1: dsB(n-half1) 4; stage B(t+1) ----
    #pragma unroll
    for (int ni = 0; ni < 2; ++ni) {
      const int row = wn * 64 + 32 + ni * 16 + m16;
      #pragma unroll
      for (int ks = 0; ks < 2; ++ks)
        bf1[ni][ks] = *(const s16x8*)(B0 + row * 128 + (((ks*4+g16) ^ (m16 & 7)) * 16));
    }
    if (t + 1 < DIM / 64) stageB((t + 1) * 64, buf ^ 1);
    SBAR();
    __builtin_amdgcn_s_setprio(1);
    #pragma unroll
    for (int mi = 0; mi < 4; ++mi)
      #pragma unroll
      for (int ni = 0; ni < 2; ++ni) {
        acc[mi][2+ni] = MFMA32(af[mi][0], bf1[ni][0], acc[mi][2+ni]);
        acc[mi][2+ni] = MFMA32(af[mi][1], bf1[ni][1], acc[mi][2+ni]);
      }
    __builtin_amdgcn_s_setprio(0);
    SBAR();

    // ---- phase 2: dsA(m-half1) 8 (reuse af regs) ----
    #pragma unroll
    for (int mi = 0; mi < 4; ++mi) {
      const int row = wm * 128 + 64 + mi * 16 + m16;
      #pragma unroll
      for (int ks = 0; ks < 2; ++ks)
        af[mi][ks] = *(const s16x8*)(A0 + row * 128 + (((ks*4+g16) ^ (m16 & 7)) * 16));
    }
    SBAR();
    __builtin_amdgcn_s_setprio(1);
    #pragma unroll
    for (int mi = 0; mi < 4; ++mi)
      #pragma unroll
      for (int ni = 0; ni < 2; ++ni) {
        acc[4+mi][ni] = MFMA32(af[mi][0], bf0[ni][0], acc[4+mi][ni]);
        acc[4+mi][ni] = MFMA32(af[mi][1], bf0[ni][1], acc[4+mi][ni]);
      }
    __builtin_amdgcn_s_setprio(0);
    SBAR();

    // ---- phase 3: MFMA only; end-of-tile sync ----
    __builtin_amdgcn_s_setprio(1);
    #pragma unroll
    for (int mi = 0; mi < 4; ++mi)
      #pragma unroll
      for (int ni = 0; ni < 2; ++ni) {
        acc[4+mi][2+ni] = MFMA32(af[mi][0], bf1[ni][0], acc[4+mi][2+ni]);
        acc[4+mi][2+ni] = MFMA32(af[mi][1], bf1[ni][1], acc[4+mi][2+ni]);
      }
    __builtin_amdgcn_s_setprio(0);
    asm volatile("s_waitcnt vmcnt(0) lgkmcnt(0)" ::: "memory");
    SBAR();
  }

  // ---- epilogue ----
  const int r0 = bm * 256 + wm * 128, c0 = bn * 256 + wn * 64;
  if (S.epi >= 3) {
    const float sc = (S.epi == 3) ? QSCALE : 1.0f;
    const int msk = (1 << S.sksh) - 1;
    #pragma unroll
    for (int ng = 0; ng < 4; ++ng) {
      const int col = c0 + ng * 16 + m16;
      const int hh = col >> 6, d = col & 63;
      const float bv = S.bias[col];
      #pragma unroll
      for (int mg = 0; mg < 8; ++mg) {
        const int rowb = r0 + mg * 16 + g16 * 4;
        #pragma unroll
        for (int r = 0; r < 4; ++r) {
          const int m = rowb + r;
          const int bb2 = m >> S.sksh, tok = m & msk;
          S.Cb[(((size_t)(bb2 * NH + hh) << S.sksh) + tok) * HD + d] =
              __float2bfloat16((acc[mg][ng][r] + bv) * sc);
        }
      }
    }
  } else {
    #pragma unroll
    for (int ng = 0; ng < 4; ++ng) {
      const int col = c0 + ng * 16 + m16;
      const float bv = S.bias[col];
      #pragma unroll
      for (int mg = 0; mg < 8; ++mg) {
        const int rowb = r0 + mg * 16 + g16 * 4;
        #pragma unroll
        for (int r = 0; r < 4; ++r) {
          float v = acc[mg][ng][r] + bv;
          const size_t idx = (size_t)(rowb + r) * DIM + col;
          if (S.epi == 1) { v = v / (1.0f + __expf(-v)); S.Cb[idx] = __float2bfloat16(v); }
          else            { S.Cb[idx] = __float2bfloat16(v); }
        }
      }
    }
  }
}

// ---------------- out-projection GEMM (m97 128x128 structure) ----------------
struct GSlot { const bf16* A; const bf16* W; const float* bias;
               const float* resid; float* Cf; };
__global__ __launch_bounds__(256) void gemm_sb(GSlot S) {
  constexpr int K = DIM;
  __shared__ alignas(16) char sA[8192];
  __shared__ alignas(16) char sB[8192];
  const int tid = threadIdx.x, lane = tid & 63, wave = tid >> 6;
  const int bm = blockIdx.x, bn = blockIdx.y;
  const int wm = wave >> 1, wn = wave & 1;
  const int m16 = lane & 15, g16 = lane >> 4;

  f32x4 acc[4][4];
  #pragma unroll
  for (int i = 0; i < 4; ++i)
    #pragma unroll
    for (int j = 0; j < 4; ++j)
      #pragma unroll
      for (int r = 0; r < 4; ++r) acc[i][j][r] = 0.0f;

  const bf16* Ab = S.A + (size_t)bm * 128 * K;
  const bf16* Wb = S.W + (size_t)bn * 128 * K;

  for (int t = 0; t < K / 32; ++t) {
    const int k0 = t * 32;
    #pragma unroll
    for (int p = 0; p < 2; ++p) {
      const int idx = p * 256 + tid;
      const int row = idx >> 2, sg = (idx & 3) ^ (row & 3);
      const size_t so = (size_t)row * K + k0 + sg * 8;
      gload16(Ab + so, &sA[p * 4096 + wave * 1024]);
      gload16(Wb + so, &sB[p * 4096 + wave * 1024]);
    }
    __syncthreads();
    s16x8 af[4], bfr[4];
    #pragma unroll
    for (int mi = 0; mi < 4; ++mi) {
      const int row = wm * 64 + mi * 16 + m16;
      af[mi] = *(const s16x8*)(&sA[row * 64 + (g16 ^ (m16 & 3)) * 16]);
    }
    #pragma unroll
    for (int ni = 0; ni < 4; ++ni) {
      const int row = wn * 64 + ni * 16 + m16;
      bfr[ni] = *(const s16x8*)(&sB[row * 64 + (g16 ^ (m16 & 3)) * 16]);
    }
    #pragma unroll
    for (int mi = 0; mi < 4; ++mi)
      #pragma unroll
      for (int ni = 0; ni < 4; ++ni)
        acc[mi][ni] = MFMA32(af[mi], bfr[ni], acc[mi][ni]);
    __syncthreads();
  }

  const int r0 = bm * 128 + wm * 64, c0 = bn * 128 + wn * 64;
  #pragma unroll
  for (int ni = 0; ni < 4; ++ni) {
    const int col = c0 + ni * 16 + m16;
    const float bv = S.bias[col];
    #pragma unroll
    for (int mi = 0; mi < 4; ++mi) {
      const int rowb = r0 + mi * 16 + g16 * 4;
      #pragma unroll
      for (int r = 0; r < 4; ++r) {
        const size_t idx = (size_t)(rowb + r) * DIM + col;
        S.Cf[idx] = acc[mi][ni][r] + bv + S.resid[idx];
      }
    }
  }
}

// ---------------- merged gate GEMV (visual + text) ---------------------------
__global__ __launch_bounds__(256) void gate2_kernel(
    const bf16* __restrict__ g1v, const bf16* __restrict__ w2v,
    const float* __restrict__ b2v, float* __restrict__ gv,
    const bf16* __restrict__ g1t, const bf16* __restrict__ w2t,
    const float* __restrict__ b2t, float* __restrict__ gt)
{
  const int lane = threadIdx.x & 63, wave = threadIdx.x >> 6;
  int row = blockIdx.x * 4 + wave;
  const bf16* x; const bf16* w2; const float* b2; float* gate;
  if (row < BB * SKV) { x = g1v + (size_t)row * DIM; w2 = w2v; b2 = b2v; gate = gv + row; }
  else { row -= BB * SKV; x = g1t + (size_t)row * DIM; w2 = w2t; b2 = b2t; gate = gt + row; }
  float sum = 0.0f;
  #pragma unroll
  for (int c = 0; c < 2; ++c) {
    const int i0 = c * 512 + lane * 8;
    const s16x8 xv = *(const s16x8*)(x + i0);
    const s16x8 wv = *(const s16x8*)(w2 + i0);
    #pragma unroll
    for (int j = 0; j < 8; ++j) sum += b2f(xv[j]) * b2f(wv[j]);
  }
  #pragma unroll
  for (int m = 32; m >= 1; m >>= 1) sum += __shfl_xor(sum, m);
  if (lane == 0) *gate = 1.0f / (1.0f + __expf(-(sum + b2[0])));
}

// ------- merged V transpose + gate fold --------------------------------------
__global__ __launch_bounds__(256) void vtrans2_kernel(
    const bf16* __restrict__ Vv, const float* __restrict__ gv, bf16* __restrict__ VTv,
    const bf16* __restrict__ Vt, const float* __restrict__ gt, bf16* __restrict__ VTt)
{
  __shared__ alignas(16) short tile[64][72];
  int kt = blockIdx.x;
  const bf16* V; const float* gate; bf16* VT; int Sk;
  if (kt < SKV / 64) { V = Vv; gate = gv; VT = VTv; Sk = SKV; }
  else { kt -= SKV / 64; V = Vt; gate = gt; VT = VTt; Sk = SKT; }
  const int h = blockIdx.y, b = blockIdx.z;
  const int tid = threadIdx.x;
  #pragma unroll
  for (int i = 0; i < 2; ++i) {
    const int c = tid + i * 256;
    const int kr = c >> 3, d0 = (c & 7) * 8;
    const float g = gate[(size_t)b * Sk + kt * 64 + kr];
    const s16x8 v = *(const s16x8*)(V + ((size_t)(b*Sk + kt*64 + kr)*NH + h)*HD + d0);
    #pragma unroll
    for (int j = 0; j < 8; ++j) tile[kr][d0 + j] = f2s(b2f(v[j]) * g);
  }
  __syncthreads();
  #pragma unroll
  for (int i = 0; i < 2; ++i) {
    const int c = tid + i * 256;
    const int d = c >> 3, k0 = (c & 7) * 8;
    s16x8 v;
    #pragma unroll
    for (int j = 0; j < 8; ++j) v[j] = tile[k0 + j][d];
    *(s16x8*)(VT + ((size_t)(b*NH + h)*HD + d)*Sk + kt*64 + k0) = v;
  }
}

// ---------------- fused dual-context flash attention (round-4 proven) --------
__global__ __launch_bounds__(256, 4) void attn_kernel(
    const bf16* __restrict__ Qh,
    const bf16* __restrict__ K1h, const bf16* __restrict__ VT1,
    const bf16* __restrict__ K2h, const bf16* __restrict__ VT2,
    bf16* __restrict__ Hout)
{
  __shared__ alignas(16) char sK[2][8192];
  __shared__ alignas(16) char sVT[2][8192];
  const int tid = threadIdx.x, lane = tid & 63, wave = tid >> 6;
  const int hb = blockIdx.x;
  const int h = hb & 15, b = hb >> 4;
  const int wq = wave & 1, hf = wave >> 1;
  const int q0 = blockIdx.y * 32 + wq * 16;
  const int m16 = lane & 15, g16 = lane >> 4;

  const bf16* qrow = Qh + ((size_t)(b*NH + h)*SQ + q0 + m16)*HD;
  const s16x8 qf0 = *(const s16x8*)(qrow + g16 * 8);
  const s16x8 qf1 = *(const s16x8*)(qrow + 32 + g16 * 8);

  const bf16* K1b  = K1h + (size_t)(b*NH + h) * SKV * HD;
  const bf16* K2b  = K2h + (size_t)(b*NH + h) * SKT * HD;
  const bf16* VT1b = VT1 + (size_t)(b*NH + h) * HD * SKV;
  const bf16* VT2b = VT2 + (size_t)(b*NH + h) * HD * SKT;

  auto stage = [&](const bf16* Kb, const bf16* VTb, int Sk, int b0, int b1) {
    #pragma unroll
    for (int p = 0; p < 2; ++p) {
      const int idx = p * 256 + tid;
      const int r = idx >> 3, g = (idx & 7) ^ (r & 7);
      gload16(Kb  + (size_t)(b0 + r) * HD + g * 8, &sK[0][p * 4096 + wave * 1024]);
      gload16(Kb  + (size_t)(b1 + r) * HD + g * 8, &sK[1][p * 4096 + wave * 1024]);
      gload16(VTb + (size_t)r * Sk + b0 + g * 8,   &sVT[0][p * 4096 + wave * 1024]);
      gload16(VTb + (size_t)r * Sk + b1 + g * 8,   &sVT[1][p * 4096 + wave * 1024]);
    }
  };

  float of[4][4];
  #pragma unroll
  for (int i = 0; i < 4; ++i)
    #pragma unroll
    for (int r = 0; r < 4; ++r) of[i][r] = 0.0f;

  f32x4 o[4];
  float mx, l;
  auto reset_state = [&]() {
    #pragma unroll
    for (int i = 0; i < 4; ++i)
      #pragma unroll
      for (int r = 0; r < 4; ++r) o[i][r] = 0.0f;
    mx = -1e30f; l = 0.0f;
  };

  auto chunk = [&]() {
    const char* kbase = &sK[hf][0];
    const char* vbase = &sVT[hf][0];
    f32x4 s[4];
    #pragma unroll
    for (int nt = 0; nt < 4; ++nt) {
      const char* kr = kbase + (nt * 16 + m16) * 128;
      const s16x8 kf0 = *(const s16x8*)(kr + ((g16    ) ^ (m16 & 7)) * 16);
      const s16x8 kf1 = *(const s16x8*)(kr + ((4 + g16) ^ (m16 & 7)) * 16);
      f32x4 a2; a2[0] = 0; a2[1] = 0; a2[2] = 0; a2[3] = 0;
      a2 = MFMA32(kf0, qf0, a2);
      a2 = MFMA32(kf1, qf1, a2);
      s[nt] = a2;
    }
    float mc = s[0][0];
    #pragma unroll
    for (int nt = 0; nt < 4; ++nt)
      #pragma unroll
      for (int r = 0; r < 4; ++r) mc = fmaxf(mc, s[nt][r]);
    mc = fmaxf(mc, __shfl_xor(mc, 16));
    mc = fmaxf(mc, __shfl_xor(mc, 32));
    const float mnew = fmaxf(mx, mc);
    const float alpha = exp2f(mx - mnew);
    mx = mnew;
    float p[4][4]; float rs = 0.0f;
    #pragma unroll
    for (int nt = 0; nt < 4; ++nt)
      #pragma unroll
      for (int r = 0; r < 4; ++r) { p[nt][r] = exp2f(s[nt][r] - mnew); rs += p[nt][r]; }
    rs += __shfl_xor(rs, 16);
    rs += __shfl_xor(rs, 32);
    l = l * alpha + rs;
    float av[4];
    #pragma unroll
    for (int r = 0; r < 4; ++r) av[r] = __shfl(alpha, g16 * 4 + r);
    #pragma unroll
    for (int nd = 0; nd < 4; ++nd)
      #pragma unroll
      for (int r = 0; r < 4; ++r) o[nd][r] *= av[r];
#if HAVE_X16
    #pragma unroll
    for (int nt = 0; nt < 4; ++nt) {
      s16x4 pa;
      pa[0] = f2s(p[nt][0]); pa[1] = f2s(p[nt][1]);
      pa[2] = f2s(p[nt][2]); pa[3] = f2s(p[nt][3]);
      #pragma unroll
      for (int nd = 0; nd < 4; ++nd) {
        const int d = nd * 16 + m16;
        const int g = (nt * 2 + (g16 >> 1)) ^ (m16 & 7);
        const s16x4 vf = *(const s16x4*)(vbase + d * 128 + g * 16 + (g16 & 1) * 8);
        o[nd] = MFMA16(pa, vf, o[nd]);
      }
    }
#endif
  };

  auto merge_flush = [&]() {
    __syncthreads();
    float* mo = (float*)&sK[0][0];
    float* ml = (float*)&sVT[0][0];
    if (hf) {
      #pragma unroll
      for (int nd = 0; nd < 4; ++nd)
        #pragma unroll
        for (int r = 0; r < 4; ++r)
          mo[(wq * 16 + g16 * 4 + r) * 64 + nd * 16 + m16] = o[nd][r];
      if (g16 == 0) { ml[(wq * 2 + 0) * 16 + m16] = mx; ml[(wq * 2 + 1) * 16 + m16] = l; }
    }
    __syncthreads();
    if (!hf) {
      const float mb = ml[(wq * 2 + 0) * 16 + m16];
      const float lb = ml[(wq * 2 + 1) * 16 + m16];
      const float ms = fmaxf(mx, mb);
      const float aA = exp2f(mx - ms), aB = exp2f(mb - ms);
      const float lt = l * aA + lb * aB;
      float aAv[4], aBv[4], ltv[4];
      #pragma unroll
      for (int r = 0; r < 4; ++r) {
        aAv[r] = __shfl(aA, g16 * 4 + r);
        aBv[r] = __shfl(aB, g16 * 4 + r);
        ltv[r] = __shfl(lt, g16 * 4 + r);
      }
      #pragma unroll
      for (int nd = 0; nd < 4; ++nd)
        #pragma unroll
        for (int r = 0; r < 4; ++r) {
          const float ob = mo[(wq * 16 + g16 * 4 + r) * 64 + nd * 16 + m16];
          of[nd][r] += (o[nd][r] * aAv[r] + ob * aBv[r]) / ltv[r];
        }
    }
    __syncthreads();
  };

  reset_state();
  for (int c = 0; c < SKV / 128; ++c) {
    stage(K1b, VT1b, SKV, c * 64, 1024 + c * 64);
    __syncthreads();
    chunk();
    __syncthreads();
  }
  merge_flush();

  reset_state();
  for (int c = 0; c < SKT / 128; ++c) {
    stage(K2b, VT2b, SKT, c * 64, 256 + c * 64);
    __syncthreads();
    chunk();
    __syncthreads();
  }
  merge_flush();

  if (!hf) {
    #pragma unroll
    for (int nd = 0; nd < 4; ++nd)
      #pragma unroll
      for (int r = 0; r < 4; ++r) {
        const int row = q0 + g16 * 4 + r;
        Hout[((size_t)(b*SQ + row)*NH + h)*HD + nd*16 + m16] =
            __float2bfloat16(of[nd][r]);
      }
  }
}

// ---------------- host launch ------------------------------------------------
extern "C" void kernel_launch(void* const* d_in, const int* in_sizes, int n_in,
                              void* d_out, int out_size, void* d_ws, size_t ws_size,
                              hipStream_t stream)
{
  const float* queries = (const float*)d_in[0];
  const float* ctx_v   = (const float*)d_in[1];
  const float* ctx_t   = (const float*)d_in[2];
  const float* w_nq = (const float*)d_in[3];
  const float* w_nv = (const float*)d_in[4];
  const float* w_nt = (const float*)d_in[5];
  const float* Wq   = (const float*)d_in[6];  const float* bq   = (const float*)d_in[7];
  const float* Wk_v = (const float*)d_in[8];  const float* bk_v = (const float*)d_in[9];
  const float* Wv_v = (const float*)d_in[10]; const float* bv_v = (const float*)d_in[11];
  const float* Wk_t = (const float*)d_in[12]; const float* bk_t = (const float*)d_in[13];
  const float* Wv_t = (const float*)d_in[14]; const float* bv_t = (const float*)d_in[15];
  const float* Wg1v = (const float*)d_in[16]; const float* bg1v = (const float*)d_in[17];
  const float* Wg2v = (const float*)d_in[18]; const float* bg2v = (const float*)d_in[19];
  const float* Wg1t = (const float*)d_in[20]; const float* bg1t = (const float*)d_in[21];
  const float* Wg2t = (const float*)d_in[22]; const float* bg2t = (const float*)d_in[23];
  const float* Wo   = (const float*)d_in[24]; const float* bo   = (const float*)d_in[25];

  char* ws = (char*)d_ws;
  size_t off = 0;
  auto alloc = [&](size_t n) { void* p = ws + off; off += (n + 255) & ~(size_t)255; return p; };

  const size_t MATB = (size_t)DIM * DIM * 2;
  bf16* WqB   = (bf16*)alloc(MATB);
  bf16* WkvB  = (bf16*)alloc(MATB);
  bf16* WvvB  = (bf16*)alloc(MATB);
  bf16* WktB  = (bf16*)alloc(MATB);
  bf16* WvtB  = (bf16*)alloc(MATB);
  bf16* Wg1vB = (bf16*)alloc(MATB);
  bf16* Wg1tB = (bf16*)alloc(MATB);
  bf16* WoB   = (bf16*)alloc(MATB);
  bf16* Wg2vB = (bf16*)alloc(2048);
  bf16* Wg2tB = (bf16*)alloc(2048);

  bf16* qn  = (bf16*)alloc((size_t)BB*SQ*DIM*2);
  bf16* cv  = (bf16*)alloc((size_t)BB*SKV*DIM*2);
  bf16* ct  = (bf16*)alloc((size_t)BB*SKT*DIM*2);
  bf16* qb  = (bf16*)alloc((size_t)BB*SQ*DIM*2);     // head-major, scaled
  bf16* kvB = (bf16*)alloc((size_t)BB*SKV*DIM*2);    // head-major
  bf16* ktB = (bf16*)alloc((size_t)BB*SKT*DIM*2);    // head-major
  bf16* vtV = (bf16*)alloc((size_t)BB*SKV*DIM*2);
  bf16* vtT = (bf16*)alloc((size_t)BB*SKT*DIM*2);
  bf16* vScrV = (bf16*)alloc((size_t)BB*SKV*DIM*2);
  bf16* vScrT = (bf16*)alloc((size_t)BB*SKT*DIM*2);
  bf16* g1V   = (bf16*)alloc((size_t)BB*SKV*DIM*2);
  bf16* g1T   = (bf16*)alloc((size_t)BB*SKT*DIM*2);
  float* gateV = (float*)alloc((size_t)BB*SKV*4);
  float* gateT = (float*)alloc((size_t)BB*SKT*4);
  bf16* hB  = (bf16*)alloc((size_t)BB*SQ*DIM*2);
  (void)ws_size; (void)n_in; (void)in_sizes; (void)out_size;

  // 1. weight casts
  CastArgs ca;
  const float* wsrc[10] = {Wq, Wk_v, Wv_v, Wk_t, Wv_t, Wg1v, Wg1t, Wo, Wg2v, Wg2t};
  bf16* wdst[10] = {WqB, WkvB, WvvB, WktB, WvtB, Wg1vB, Wg1tB, WoB, Wg2vB, Wg2tB};
  for (int i = 0; i < 10; ++i) {
    ca.src[i] = wsrc[i]; ca.dst[i] = wdst[i];
    ca.n[i] = (i < 8) ? DIM * DIM : DIM;
  }
  cast_kernel<<<dim3(1024, 10), 256, 0, stream>>>(ca);

  // 2. RMSNorms
  NormArgs na;
  na.x[0] = queries; na.x[1] = ctx_v; na.x[2] = ctx_t;
  na.w[0] = w_nq;    na.w[1] = w_nv;  na.w[2] = w_nt;
  na.y[0] = qn;      na.y[1] = cv;    na.y[2] = ct;
  na.rows[0] = BB*SQ; na.rows[1] = BB*SKV; na.rows[2] = BB*SKT;
  rmsnorm_kernel<<<dim3(BB*SKV, 3), 256, 0, stream>>>(na);

  // 3. ALL 7 projections in one 256^2 pipelined dispatch
  PArgs pa;
  pa.s[0] = {cv, WkvB,  bk_v, kvB,   4, 11};   // K visual, head-major
  pa.s[1] = {cv, WvvB,  bv_v, vScrV, 0, 0};    // V visual
  pa.s[2] = {cv, Wg1vB, bg1v, g1V,   1, 0};    // G1 visual (silu)
  pa.s[3] = {qn, WqB,   bq,   qb,    3, 9};    // Q, head-major + scale
  pa.s[4] = {ct, WktB,  bk_t, ktB,   4, 9};    // K text, head-major
  pa.s[5] = {ct, WvtB,  bv_t, vScrT, 0, 0};    // V text
  pa.s[6] = {ct, Wg1tB, bg1t, g1T,   1, 0};    // G1 text (silu)
  proj256<<<dim3(512), 512, 0, stream>>>(pa);

  // 4. gates (both contexts) + gated V transpose (both contexts)
  gate2_kernel<<<dim3((BB*SKV + BB*SKT) / 4), 256, 0, stream>>>(
      g1V, Wg2vB, bg2v, gateV, g1T, Wg2tB, bg2t, gateT);
  vtrans2_kernel<<<dim3(SKV/64 + SKT/64, NH, BB), 256, 0, stream>>>(
      vScrV, gateV, vtV, vScrT, gateT, vtT);

  // 5. fused dual-context attention
  attn_kernel<<<dim3(NH*BB, SQ/32), 256, 0, stream>>>(qb, kvB, vtV, ktB, vtT, hB);

  // 6. output projection + residual (f32 out)
  GSlot go{hB, WoB, bo, queries, (float*)d_out};
  gemm_sb<<<dim3(BB*SQ/128, 8), 256, 0, stream>>>(go);
}

// Round 6
// 203.380 us; speedup vs baseline: 1.4143x; 1.0523x over previous
//
#include <hip/hip_runtime.h>
#include <hip/hip_bf16.h>

typedef __attribute__((ext_vector_type(4))) float f32x4;
typedef __attribute__((ext_vector_type(8))) short s16x8;
typedef __attribute__((ext_vector_type(4))) short s16x4;
using bf16 = __hip_bfloat16;

static constexpr int BB  = 4;
static constexpr int SQ  = 512;
static constexpr int SKV = 2048;
static constexpr int SKT = 512;
static constexpr int DIM = 1024;
static constexpr int NH  = 16;
static constexpr int HD  = 64;

#define MFMA32(A,B,C) __builtin_amdgcn_mfma_f32_16x16x32_bf16(A,B,C,0,0,0)

#if __has_builtin(__builtin_amdgcn_mfma_f32_16x16x16_bf16)
  #define MFMA16(A,B,C) __builtin_amdgcn_mfma_f32_16x16x16_bf16(A,B,C,0,0,0)
  #define HAVE_X16 1
#elif __has_builtin(__builtin_amdgcn_mfma_f32_16x16x16bf16_1k)
  #define MFMA16(A,B,C) __builtin_amdgcn_mfma_f32_16x16x16bf16_1k(A,B,C,0,0,0)
  #define HAVE_X16 1
#else
  #define HAVE_X16 0
#endif

#define SBAR() asm volatile("s_barrier" ::: "memory")

__device__ __forceinline__ float b2f(short s) {
  unsigned int u = ((unsigned int)(unsigned short)s) << 16;
  float f; __builtin_memcpy(&f, &u, 4); return f;
}
__device__ __forceinline__ short f2s(float f) {
  bf16 h = __float2bfloat16(f); short s; __builtin_memcpy(&s, &h, 2); return s;
}

__device__ __forceinline__ void gload16(const void* g, void* l) {
  __builtin_amdgcn_global_load_lds(
      (const __attribute__((address_space(1))) void*)g,
      (__attribute__((address_space(3))) void*)l, 16, 0, 0);
}

static constexpr float QSCALE = 0.180336880111120426f;  // 0.125 * log2(e)

// --------- merged prep: weight cast f32->bf16  +  RMSNorm (one launch) ------
struct PrepArgs {
  const float* csrc[10]; bf16* cdst[10]; int cn[10];
  const float* nx[3]; const float* nw[3]; bf16* ny[3];
};
__global__ __launch_bounds__(256) void prep_kernel(PrepArgs a) {
  const int bx = blockIdx.x;
  if (bx < 10240) {
    const int y = bx >> 10;
    const int i = ((bx & 1023) * 256 + threadIdx.x) * 4;
    if (i >= a.cn[y]) return;
    const float4 v = *(const float4*)(a.csrc[y] + i);
    bf16* d = a.cdst[y] + i;
    d[0] = __float2bfloat16(v.x); d[1] = __float2bfloat16(v.y);
    d[2] = __float2bfloat16(v.z); d[3] = __float2bfloat16(v.w);
    return;
  }
  const int j = bx - 10240;
  int t, row;
  if (j < 2048) { t = 0; row = j; }
  else if (j < 10240) { t = 1; row = j - 2048; }
  else { t = 2; row = j - 10240; }
  const float* x = a.nx[t] + (size_t)row * DIM;
  const float4 v = *(const float4*)(x + threadIdx.x * 4);
  float ss = v.x*v.x + v.y*v.y + v.z*v.z + v.w*v.w;
  #pragma unroll
  for (int m = 32; m >= 1; m >>= 1) ss += __shfl_xor(ss, m);
  __shared__ float red[4];
  if ((threadIdx.x & 63) == 0) red[threadIdx.x >> 6] = ss;
  __syncthreads();
  ss = red[0] + red[1] + red[2] + red[3];
  const float sc = rsqrtf(ss * (1.0f / DIM) + 1.1920928955078125e-07f);
  const float4 w = *(const float4*)(a.nw[t] + threadIdx.x * 4);
  bf16* y = a.ny[t] + (size_t)row * DIM + threadIdx.x * 4;
  y[0] = __float2bfloat16(v.x * sc * w.x);
  y[1] = __float2bfloat16(v.y * sc * w.y);
  y[2] = __float2bfloat16(v.z * sc * w.z);
  y[3] = __float2bfloat16(v.w * sc * w.w);
}

// ============== 256x256 8-wave pipelined projection GEMM =====================
// BK=64, 2-deep K-tile prefetch, counted vmcnt(8) (T4: loads fly across
// barriers, never drained mid-loop), stage issue split across phases 2/3
// into just-freed LDS regions. 7 slots flat-decoded, XCD-bijective swizzle.
struct PSlot { const bf16* A; const bf16* W; const float* bias;
               bf16* Cb; int epi; int sksh; };
struct PArgs { PSlot s[7]; };

__global__ __launch_bounds__(512, 2) void proj256(PArgs a) {
  __shared__ char lds[131072];   // [buf][A 32KB | B 32KB]
  const int tid = threadIdx.x, lane = tid & 63, wave = tid >> 6;
  const int m16 = lane & 15, g16 = lane >> 4;
  const int wm = wave >> 2, wn = wave & 3;

  // XCD-bijective swizzle (512 % 8 == 0) + slot decode (bn fastest)
  const int i = (blockIdx.x & 7) * 64 + (blockIdx.x >> 3);
  int slot, rem;
  if (i < 384) { slot = i >> 7; rem = i & 127; }
  else { const int j = i - 384; slot = 3 + (j >> 5); rem = j & 31; }
  const PSlot S = a.s[slot];
  const int bn = rem & 3, bm = rem >> 2;

  const bf16* Ab = S.A + (size_t)bm * 256 * DIM;
  const bf16* Wb = S.W + (size_t)bn * 256 * DIM;

  auto stageA = [&](int k0, int buf) {
    #pragma unroll
    for (int q = 0; q < 4; ++q) {
      const int idx = q * 512 + tid;
      const int row = idx >> 3, g = (idx & 7) ^ (row & 7);
      gload16(Ab + (size_t)row * DIM + k0 + g * 8,
              &lds[buf * 65536 + q * 8192 + wave * 1024]);
    }
  };
  auto stageB = [&](int k0, int buf) {
    #pragma unroll
    for (int q = 0; q < 4; ++q) {
      const int idx = q * 512 + tid;
      const int row = idx >> 3, g = (idx & 7) ^ (row & 7);
      gload16(Wb + (size_t)row * DIM + k0 + g * 8,
              &lds[buf * 65536 + 32768 + q * 8192 + wave * 1024]);
    }
  };

  f32x4 acc[8][4];
  #pragma unroll
  for (int x = 0; x < 8; ++x)
    #pragma unroll
    for (int y = 0; y < 4; ++y)
      #pragma unroll
      for (int r = 0; r < 4; ++r) acc[x][y][r] = 0.0f;

  // prologue: stage tiles 0 and 1 (16 loads), wait for tile 0 only
  stageA(0, 0); stageB(0, 0);
  stageA(64, 1); stageB(64, 1);
  asm volatile("s_waitcnt vmcnt(8)" ::: "memory");
  SBAR();

  constexpr int NT = DIM / 64;   // 16
  for (int t = 0; t < NT; ++t) {
    const int buf = t & 1;
    const char* A0 = &lds[buf * 65536];
    const char* B0 = A0 + 32768;
    s16x8 af[4][2], bf0[2][2], bf1[2][2];

    // ---- phase 0: dsA(m-half0) 8 + dsB(n-half0) 4 ----
    #pragma unroll
    for (int mi = 0; mi < 4; ++mi) {
      const int row = wm * 128 + mi * 16 + m16;
      #pragma unroll
      for (int ks = 0; ks < 2; ++ks)
        af[mi][ks] = *(const s16x8*)(A0 + row * 128 + (((ks*4+g16) ^ (m16 & 7)) * 16));
    }
    #pragma unroll
    for (int ni = 0; ni < 2; ++ni) {
      const int row = wn * 64 + ni * 16 + m16;
      #pragma unroll
      for (int ks = 0; ks < 2; ++ks)
        bf0[ni][ks] = *(const s16x8*)(B0 + row * 128 + (((ks*4+g16) ^ (m16 & 7)) * 16));
    }
    SBAR();
    __builtin_amdgcn_s_setprio(1);
    #pragma unroll
    for (int mi = 0; mi < 4; ++mi)
      #pragma unroll
      for (int ni = 0; ni < 2; ++ni) {
        acc[mi][ni] = MFMA32(af[mi][0], bf0[ni][0], acc[mi][ni]);
        acc[mi][ni] = MFMA32(af[mi][1], bf0[ni][1], acc[mi][ni]);
      }
    __builtin_amdgcn_s_setprio(0);
    SBAR();

    // ---- phase 1: dsB(n-half1) 4 ----
    #pragma unroll
    for (int ni = 0; ni < 2; ++ni) {
      const int row = wn * 64 + 32 + ni * 16 + m16;
      #pragma unroll
      for (int ks = 0; ks < 2; ++ks)
        bf1[ni][ks] = *(const s16x8*)(B0 + row * 128 + (((ks*4+g16) ^ (m16 & 7)) * 16));
    }
    SBAR();
    __builtin_amdgcn_s_setprio(1);
    #pragma unroll
    for (int mi = 0; mi < 4; ++mi)
      #pragma unroll
      for (int ni = 0; ni < 2; ++ni) {
        acc[mi][2+ni] = MFMA32(af[mi][0], bf1[ni][0], acc[mi][2+ni]);
        acc[mi][2+ni] = MFMA32(af[mi][1], bf1[ni][1], acc[mi][2+ni]);
      }
    __builtin_amdgcn_s_setprio(0);
    SBAR();   // <- B-region of buf now dead (bf0/bf1 in regs)

    // ---- phase 2: stage B(t+2) into freed B-region; dsA(m-half1) 8 ----
    if (t + 2 < NT) stageB((t + 2) * 64, buf);
    #pragma unroll
    for (int mi = 0; mi < 4; ++mi) {
      const int row = wm * 128 + 64 + mi * 16 + m16;
      #pragma unroll
      for (int ks = 0; ks < 2; ++ks)
        af[mi][ks] = *(const s16x8*)(A0 + row * 128 + (((ks*4+g16) ^ (m16 & 7)) * 16));
    }
    SBAR();
    __builtin_amdgcn_s_setprio(1);
    #pragma unroll
    for (int mi = 0; mi < 4; ++mi)
      #pragma unroll
      for (int ni = 0; ni < 2; ++ni) {
        acc[4+mi][ni] = MFMA32(af[mi][0], bf0[ni][0], acc[4+mi][ni]);
        acc[4+mi][ni] = MFMA32(af[mi][1], bf0[ni][1], acc[4+mi][ni]);
      }
    __builtin_amdgcn_s_setprio(0);
    SBAR();   // <- A-region of buf now dead (af half1 consumed)

    // ---- phase 3: stage A(t+2) into freed A-region; MFMA-only ----
    if (t + 2 < NT) stageA((t + 2) * 64, buf);
    __builtin_amdgcn_s_setprio(1);
    #pragma unroll
    for (int mi = 0; mi < 4; ++mi)
      #pragma unroll
      for (int ni = 0; ni < 2; ++ni) {
        acc[4+mi][2+ni] = MFMA32(af[mi][0], bf1[ni][0], acc[4+mi][2+ni]);
        acc[4+mi][2+ni] = MFMA32(af[mi][1], bf1[ni][1], acc[4+mi][2+ni]);
      }
    __builtin_amdgcn_s_setprio(0);
    // counted wait: t+1's 8 loads must land; t+2's 8 stay in flight
    if (t < NT - 2)       { asm volatile("s_waitcnt vmcnt(8)" ::: "memory"); }
    else if (t == NT - 2) { asm volatile("s_waitcnt vmcnt(0)" ::: "memory"); }
    SBAR();
  }

  // ---- epilogue ----
  const int r0 = bm * 256 + wm * 128, c0 = bn * 256 + wn * 64;
  if (S.epi >= 3) {
    const float sc = (S.epi == 3) ? QSCALE : 1.0f;
    const int msk = (1 << S.sksh) - 1;
    #pragma unroll
    for (int ng = 0; ng < 4; ++ng) {
      const int col = c0 + ng * 16 + m16;
      const int hh = col >> 6, d = col & 63;
      const float bv = S.bias[col];
      #pragma unroll
      for (int mg = 0; mg < 8; ++mg) {
        const int rowb = r0 + mg * 16 + g16 * 4;
        #pragma unroll
        for (int r = 0; r < 4; ++r) {
          const int m = rowb + r;
          const int bb2 = m >> S.sksh, tok = m & msk;
          S.Cb[(((size_t)(bb2 * NH + hh) << S.sksh) + tok) * HD + d] =
              __float2bfloat16((acc[mg][ng][r] + bv) * sc);
        }
      }
    }
  } else {
    #pragma unroll
    for (int ng = 0; ng < 4; ++ng) {
      const int col = c0 + ng * 16 + m16;
      const float bv = S.bias[col];
      #pragma unroll
      for (int mg = 0; mg < 8; ++mg) {
        const int rowb = r0 + mg * 16 + g16 * 4;
        #pragma unroll
        for (int r = 0; r < 4; ++r) {
          float v = acc[mg][ng][r] + bv;
          const size_t idx = (size_t)(rowb + r) * DIM + col;
          if (S.epi == 1) { v = v / (1.0f + __expf(-v)); S.Cb[idx] = __float2bfloat16(v); }
          else            { S.Cb[idx] = __float2bfloat16(v); }
        }
      }
    }
  }
}

// -------- out-projection GEMM: 64x128 tile, 256 blocks (full CU fill) --------
struct GSlot { const bf16* A; const bf16* W; const float* bias;
               const float* resid; float* Cf; };
__global__ __launch_bounds__(256) void gemm_out(GSlot S) {
  constexpr int K = DIM;
  __shared__ alignas(16) char sA[4096];
  __shared__ alignas(16) char sB[8192];
  const int tid = threadIdx.x, lane = tid & 63, wave = tid >> 6;
  const int bm = blockIdx.x, bn = blockIdx.y;
  const int m16 = lane & 15, g16 = lane >> 4;

  f32x4 acc[4][2];
  #pragma unroll
  for (int i = 0; i < 4; ++i)
    #pragma unroll
    for (int j = 0; j < 2; ++j)
      #pragma unroll
      for (int r = 0; r < 4; ++r) acc[i][j][r] = 0.0f;

  const bf16* Ab = S.A + (size_t)bm * 64 * K;
  const bf16* Wb = S.W + (size_t)bn * 128 * K;

  for (int t = 0; t < K / 32; ++t) {
    const int k0 = t * 32;
    {
      const int row = tid >> 2, sg = (tid & 3) ^ (row & 3);
      gload16(Ab + (size_t)row * K + k0 + sg * 8, &sA[wave * 1024]);
    }
    #pragma unroll
    for (int p = 0; p < 2; ++p) {
      const int idx = p * 256 + tid;
      const int row = idx >> 2, sg = (idx & 3) ^ (row & 3);
      gload16(Wb + (size_t)row * K + k0 + sg * 8, &sB[p * 4096 + wave * 1024]);
    }
    __syncthreads();
    s16x8 af[4], bfr[2];
    #pragma unroll
    for (int mi = 0; mi < 4; ++mi) {
      const int row = mi * 16 + m16;
      af[mi] = *(const s16x8*)(&sA[row * 64 + (g16 ^ (m16 & 3)) * 16]);
    }
    #pragma unroll
    for (int ni = 0; ni < 2; ++ni) {
      const int row = wave * 32 + ni * 16 + m16;
      bfr[ni] = *(const s16x8*)(&sB[row * 64 + (g16 ^ (m16 & 3)) * 16]);
    }
    #pragma unroll
    for (int mi = 0; mi < 4; ++mi)
      #pragma unroll
      for (int ni = 0; ni < 2; ++ni)
        acc[mi][ni] = MFMA32(af[mi], bfr[ni], acc[mi][ni]);
    __syncthreads();
  }

  const int r0 = bm * 64, c0 = bn * 128 + wave * 32;
  #pragma unroll
  for (int ni = 0; ni < 2; ++ni) {
    const int col = c0 + ni * 16 + m16;
    const float bv = S.bias[col];
    #pragma unroll
    for (int mi = 0; mi < 4; ++mi) {
      const int rowb = r0 + mi * 16 + g16 * 4;
      #pragma unroll
      for (int r = 0; r < 4; ++r) {
        const size_t idx = (size_t)(rowb + r) * DIM + col;
        S.Cf[idx] = acc[mi][ni][r] + bv + S.resid[idx];
      }
    }
  }
}

// ---------------- merged gate GEMV (visual + text) ---------------------------
__global__ __launch_bounds__(256) void gate2_kernel(
    const bf16* __restrict__ g1v, const bf16* __restrict__ w2v,
    const float* __restrict__ b2v, float* __restrict__ gv,
    const bf16* __restrict__ g1t, const bf16* __restrict__ w2t,
    const float* __restrict__ b2t, float* __restrict__ gt)
{
  const int lane = threadIdx.x & 63, wave = threadIdx.x >> 6;
  int row = blockIdx.x * 4 + wave;
  const bf16* x; const bf16* w2; const float* b2; float* gate;
  if (row < BB * SKV) { x = g1v + (size_t)row * DIM; w2 = w2v; b2 = b2v; gate = gv + row; }
  else { row -= BB * SKV; x = g1t + (size_t)row * DIM; w2 = w2t; b2 = b2t; gate = gt + row; }
  float sum = 0.0f;
  #pragma unroll
  for (int c = 0; c < 2; ++c) {
    const int i0 = c * 512 + lane * 8;
    const s16x8 xv = *(const s16x8*)(x + i0);
    const s16x8 wv = *(const s16x8*)(w2 + i0);
    #pragma unroll
    for (int j = 0; j < 8; ++j) sum += b2f(xv[j]) * b2f(wv[j]);
  }
  #pragma unroll
  for (int m = 32; m >= 1; m >>= 1) sum += __shfl_xor(sum, m);
  if (lane == 0) *gate = 1.0f / (1.0f + __expf(-(sum + b2[0])));
}

// ------- merged V transpose + gate fold --------------------------------------
__global__ __launch_bounds__(256) void vtrans2_kernel(
    const bf16* __restrict__ Vv, const float* __restrict__ gv, bf16* __restrict__ VTv,
    const bf16* __restrict__ Vt, const float* __restrict__ gt, bf16* __restrict__ VTt)
{
  __shared__ alignas(16) short tile[64][72];
  int kt = blockIdx.x;
  const bf16* V; const float* gate; bf16* VT; int Sk;
  if (kt < SKV / 64) { V = Vv; gate = gv; VT = VTv; Sk = SKV; }
  else { kt -= SKV / 64; V = Vt; gate = gt; VT = VTt; Sk = SKT; }
  const int h = blockIdx.y, b = blockIdx.z;
  const int tid = threadIdx.x;
  #pragma unroll
  for (int i = 0; i < 2; ++i) {
    const int c = tid + i * 256;
    const int kr = c >> 3, d0 = (c & 7) * 8;
    const float g = gate[(size_t)b * Sk + kt * 64 + kr];
    const s16x8 v = *(const s16x8*)(V + ((size_t)(b*Sk + kt*64 + kr)*NH + h)*HD + d0);
    #pragma unroll
    for (int j = 0; j < 8; ++j) tile[kr][d0 + j] = f2s(b2f(v[j]) * g);
  }
  __syncthreads();
  #pragma unroll
  for (int i = 0; i < 2; ++i) {
    const int c = tid + i * 256;
    const int d = c >> 3, k0 = (c & 7) * 8;
    s16x8 v;
    #pragma unroll
    for (int j = 0; j < 8; ++j) v[j] = tile[k0 + j][d];
    *(s16x8*)(VT + ((size_t)(b*NH + h)*HD + d)*Sk + kt*64 + k0) = v;
  }
}

// ---------------- fused dual-context flash attention (round-4 proven) --------
__global__ __launch_bounds__(256, 4) void attn_kernel(
    const bf16* __restrict__ Qh,
    const bf16* __restrict__ K1h, const bf16* __restrict__ VT1,
    const bf16* __restrict__ K2h, const bf16* __restrict__ VT2,
    bf16* __restrict__ Hout)
{
  __shared__ alignas(16) char sK[2][8192];
  __shared__ alignas(16) char sVT[2][8192];
  const int tid = threadIdx.x, lane = tid & 63, wave = tid >> 6;
  const int hb = blockIdx.x;
  const int h = hb & 15, b = hb >> 4;
  const int wq = wave & 1, hf = wave >> 1;
  const int q0 = blockIdx.y * 32 + wq * 16;
  const int m16 = lane & 15, g16 = lane >> 4;

  const bf16* qrow = Qh + ((size_t)(b*NH + h)*SQ + q0 + m16)*HD;
  const s16x8 qf0 = *(const s16x8*)(qrow + g16 * 8);
  const s16x8 qf1 = *(const s16x8*)(qrow + 32 + g16 * 8);

  const bf16* K1b  = K1h + (size_t)(b*NH + h) * SKV * HD;
  const bf16* K2b  = K2h + (size_t)(b*NH + h) * SKT * HD;
  const bf16* VT1b = VT1 + (size_t)(b*NH + h) * HD * SKV;
  const bf16* VT2b = VT2 + (size_t)(b*NH + h) * HD * SKT;

  auto stage = [&](const bf16* Kb, const bf16* VTb, int Sk, int b0, int b1) {
    #pragma unroll
    for (int p = 0; p < 2; ++p) {
      const int idx = p * 256 + tid;
      const int r = idx >> 3, g = (idx & 7) ^ (r & 7);
      gload16(Kb  + (size_t)(b0 + r) * HD + g * 8, &sK[0][p * 4096 + wave * 1024]);
      gload16(Kb  + (size_t)(b1 + r) * HD + g * 8, &sK[1][p * 4096 + wave * 1024]);
      gload16(VTb + (size_t)r * Sk + b0 + g * 8,   &sVT[0][p * 4096 + wave * 1024]);
      gload16(VTb + (size_t)r * Sk + b1 + g * 8,   &sVT[1][p * 4096 + wave * 1024]);
    }
  };

  float of[4][4];
  #pragma unroll
  for (int i = 0; i < 4; ++i)
    #pragma unroll
    for (int r = 0; r < 4; ++r) of[i][r] = 0.0f;

  f32x4 o[4];
  float mx, l;
  auto reset_state = [&]() {
    #pragma unroll
    for (int i = 0; i < 4; ++i)
      #pragma unroll
      for (int r = 0; r < 4; ++r) o[i][r] = 0.0f;
    mx = -1e30f; l = 0.0f;
  };

  auto chunk = [&]() {
    const char* kbase = &sK[hf][0];
    const char* vbase = &sVT[hf][0];
    f32x4 s[4];
    #pragma unroll
    for (int nt = 0; nt < 4; ++nt) {
      const char* kr = kbase + (nt * 16 + m16) * 128;
      const s16x8 kf0 = *(const s16x8*)(kr + ((g16    ) ^ (m16 & 7)) * 16);
      const s16x8 kf1 = *(const s16x8*)(kr + ((4 + g16) ^ (m16 & 7)) * 16);
      f32x4 a2; a2[0] = 0; a2[1] = 0; a2[2] = 0; a2[3] = 0;
      a2 = MFMA32(kf0, qf0, a2);
      a2 = MFMA32(kf1, qf1, a2);
      s[nt] = a2;
    }
    float mc = s[0][0];
    #pragma unroll
    for (int nt = 0; nt < 4; ++nt)
      #pragma unroll
      for (int r = 0; r < 4; ++r) mc = fmaxf(mc, s[nt][r]);
    mc = fmaxf(mc, __shfl_xor(mc, 16));
    mc = fmaxf(mc, __shfl_xor(mc, 32));
    const float mnew = fmaxf(mx, mc);
    const float alpha = exp2f(mx - mnew);
    mx = mnew;
    float p[4][4]; float rs = 0.0f;
    #pragma unroll
    for (int nt = 0; nt < 4; ++nt)
      #pragma unroll
      for (int r = 0; r < 4; ++r) { p[nt][r] = exp2f(s[nt][r] - mnew); rs += p[nt][r]; }
    rs += __shfl_xor(rs, 16);
    rs += __shfl_xor(rs, 32);
    l = l * alpha + rs;
    float av[4];
    #pragma unroll
    for (int r = 0; r < 4; ++r) av[r] = __shfl(alpha, g16 * 4 + r);
    #pragma unroll
    for (int nd = 0; nd < 4; ++nd)
      #pragma unroll
      for (int r = 0; r < 4; ++r) o[nd][r] *= av[r];
#if HAVE_X16
    #pragma unroll
    for (int nt = 0; nt < 4; ++nt) {
      s16x4 pa;
      pa[0] = f2s(p[nt][0]); pa[1] = f2s(p[nt][1]);
      pa[2] = f2s(p[nt][2]); pa[3] = f2s(p[nt][3]);
      #pragma unroll
      for (int nd = 0; nd < 4; ++nd) {
        const int d = nd * 16 + m16;
        const int g = (nt * 2 + (g16 >> 1)) ^ (m16 & 7);
        const s16x4 vf = *(const s16x4*)(vbase + d * 128 + g * 16 + (g16 & 1) * 8);
        o[nd] = MFMA16(pa, vf, o[nd]);
      }
    }
#endif
  };

  auto merge_flush = [&]() {
    __syncthreads();
    float* mo = (float*)&sK[0][0];
    float* ml = (float*)&sVT[0][0];
    if (hf) {
      #pragma unroll
      for (int nd = 0; nd < 4; ++nd)
        #pragma unroll
        for (int r = 0; r < 4; ++r)
          mo[(wq * 16 + g16 * 4 + r) * 64 + nd * 16 + m16] = o[nd][r];
      if (g16 == 0) { ml[(wq * 2 + 0) * 16 + m16] = mx; ml[(wq * 2 + 1) * 16 + m16] = l; }
    }
    __syncthreads();
    if (!hf) {
      const float mb = ml[(wq * 2 + 0) * 16 + m16];
      const float lb = ml[(wq * 2 + 1) * 16 + m16];
      const float ms = fmaxf(mx, mb);
      const float aA = exp2f(mx - ms), aB = exp2f(mb - ms);
      const float lt = l * aA + lb * aB;
      float aAv[4], aBv[4], ltv[4];
      #pragma unroll
      for (int r = 0; r < 4; ++r) {
        aAv[r] = __shfl(aA, g16 * 4 + r);
        aBv[r] = __shfl(aB, g16 * 4 + r);
        ltv[r] = __shfl(lt, g16 * 4 + r);
      }
      #pragma unroll
      for (int nd = 0; nd < 4; ++nd)
        #pragma unroll
        for (int r = 0; r < 4; ++r) {
          const float ob = mo[(wq * 16 + g16 * 4 + r) * 64 + nd * 16 + m16];
          of[nd][r] += (o[nd][r] * aAv[r] + ob * aBv[r]) / ltv[r];
        }
    }
    __syncthreads();
  };

  reset_state();
  for (int c = 0; c < SKV / 128; ++c) {
    stage(K1b, VT1b, SKV, c * 64, 1024 + c * 64);
    __syncthreads();
    chunk();
    __syncthreads();
  }
  merge_flush();

  reset_state();
  for (int c = 0; c < SKT / 128; ++c) {
    stage(K2b, VT2b, SKT, c * 64, 256 + c * 64);
    __syncthreads();
    chunk();
    __syncthreads();
  }
  merge_flush();

  if (!hf) {
    #pragma unroll
    for (int nd = 0; nd < 4; ++nd)
      #pragma unroll
      for (int r = 0; r < 4; ++r) {
        const int row = q0 + g16 * 4 + r;
        Hout[((size_t)(b*SQ + row)*NH + h)*HD + nd*16 + m16] =
            __float2bfloat16(of[nd][r]);
      }
  }
}

// ---------------- host launch ------------------------------------------------
extern "C" void kernel_launch(void* const* d_in, const int* in_sizes, int n_in,
                              void* d_out, int out_size, void* d_ws, size_t ws_size,
                              hipStream_t stream)
{
  const float* queries = (const float*)d_in[0];
  const float* ctx_v   = (const float*)d_in[1];
  const float* ctx_t   = (const float*)d_in[2];
  const float* w_nq = (const float*)d_in[3];
  const float* w_nv = (const float*)d_in[4];
  const float* w_nt = (const float*)d_in[5];
  const float* Wq   = (const float*)d_in[6];  const float* bq   = (const float*)d_in[7];
  const float* Wk_v = (const float*)d_in[8];  const float* bk_v = (const float*)d_in[9];
  const float* Wv_v = (const float*)d_in[10]; const float* bv_v = (const float*)d_in[11];
  const float* Wk_t = (const float*)d_in[12]; const float* bk_t = (const float*)d_in[13];
  const float* Wv_t = (const float*)d_in[14]; const float* bv_t = (const float*)d_in[15];
  const float* Wg1v = (const float*)d_in[16]; const float* bg1v = (const float*)d_in[17];
  const float* Wg2v = (const float*)d_in[18]; const float* bg2v = (const float*)d_in[19];
  const float* Wg1t = (const float*)d_in[20]; const float* bg1t = (const float*)d_in[21];
  const float* Wg2t = (const float*)d_in[22]; const float* bg2t = (const float*)d_in[23];
  const float* Wo   = (const float*)d_in[24]; const float* bo   = (const float*)d_in[25];

  char* ws = (char*)d_ws;
  size_t off = 0;
  auto alloc = [&](size_t n) { void* p = ws + off; off += (n + 255) & ~(size_t)255; return p; };

  const size_t MATB = (size_t)DIM * DIM * 2;
  bf16* WqB   = (bf16*)alloc(MATB);
  bf16* WkvB  = (bf16*)alloc(MATB);
  bf16* WvvB  = (bf16*)alloc(MATB);
  bf16* WktB  = (bf16*)alloc(MATB);
  bf16* WvtB  = (bf16*)alloc(MATB);
  bf16* Wg1vB = (bf16*)alloc(MATB);
  bf16* Wg1tB = (bf16*)alloc(MATB);
  bf16* WoB   = (bf16*)alloc(MATB);
  bf16* Wg2vB = (bf16*)alloc(2048);
  bf16* Wg2tB = (bf16*)alloc(2048);

  bf16* qn  = (bf16*)alloc((size_t)BB*SQ*DIM*2);
  bf16* cv  = (bf16*)alloc((size_t)BB*SKV*DIM*2);
  bf16* ct  = (bf16*)alloc((size_t)BB*SKT*DIM*2);
  bf16* qb  = (bf16*)alloc((size_t)BB*SQ*DIM*2);     // head-major, scaled
  bf16* kvB = (bf16*)alloc((size_t)BB*SKV*DIM*2);    // head-major
  bf16* ktB = (bf16*)alloc((size_t)BB*SKT*DIM*2);    // head-major
  bf16* vtV = (bf16*)alloc((size_t)BB*SKV*DIM*2);
  bf16* vtT = (bf16*)alloc((size_t)BB*SKT*DIM*2);
  bf16* vScrV = (bf16*)alloc((size_t)BB*SKV*DIM*2);
  bf16* vScrT = (bf16*)alloc((size_t)BB*SKT*DIM*2);
  bf16* g1V   = (bf16*)alloc((size_t)BB*SKV*DIM*2);
  bf16* g1T   = (bf16*)alloc((size_t)BB*SKT*DIM*2);
  float* gateV = (float*)alloc((size_t)BB*SKV*4);
  float* gateT = (float*)alloc((size_t)BB*SKT*4);
  bf16* hB  = (bf16*)alloc((size_t)BB*SQ*DIM*2);
  (void)ws_size; (void)n_in; (void)in_sizes; (void)out_size;

  // 1. weight casts + RMSNorms in ONE launch
  PrepArgs pr;
  const float* wsrc[10] = {Wq, Wk_v, Wv_v, Wk_t, Wv_t, Wg1v, Wg1t, Wo, Wg2v, Wg2t};
  bf16* wdst[10] = {WqB, WkvB, WvvB, WktB, WvtB, Wg1vB, Wg1tB, WoB, Wg2vB, Wg2tB};
  for (int i = 0; i < 10; ++i) {
    pr.csrc[i] = wsrc[i]; pr.cdst[i] = wdst[i];
    pr.cn[i] = (i < 8) ? DIM * DIM : DIM;
  }
  pr.nx[0] = queries; pr.nx[1] = ctx_v; pr.nx[2] = ctx_t;
  pr.nw[0] = w_nq;    pr.nw[1] = w_nv;  pr.nw[2] = w_nt;
  pr.ny[0] = qn;      pr.ny[1] = cv;    pr.ny[2] = ct;
  prep_kernel<<<dim3(10240 + 12288), 256, 0, stream>>>(pr);

  // 2. ALL 7 projections in one 256^2 pipelined dispatch (counted vmcnt)
  PArgs pa;
  pa.s[0] = {cv, WkvB,  bk_v, kvB,   4, 11};   // K visual, head-major
  pa.s[1] = {cv, WvvB,  bv_v, vScrV, 0, 0};    // V visual
  pa.s[2] = {cv, Wg1vB, bg1v, g1V,   1, 0};    // G1 visual (silu)
  pa.s[3] = {qn, WqB,   bq,   qb,    3, 9};    // Q, head-major + scale
  pa.s[4] = {ct, WktB,  bk_t, ktB,   4, 9};    // K text, head-major
  pa.s[5] = {ct, WvtB,  bv_t, vScrT, 0, 0};    // V text
  pa.s[6] = {ct, Wg1tB, bg1t, g1T,   1, 0};    // G1 text (silu)
  proj256<<<dim3(512), 512, 0, stream>>>(pa);

  // 3. gates (both contexts) + gated V transpose (both contexts)
  gate2_kernel<<<dim3((BB*SKV + BB*SKT) / 4), 256, 0, stream>>>(
      g1V, Wg2vB, bg2v, gateV, g1T, Wg2tB, bg2t, gateT);
  vtrans2_kernel<<<dim3(SKV/64 + SKT/64, NH, BB), 256, 0, stream>>>(
      vScrV, gateV, vtV, vScrT, gateT, vtT);

  // 4. fused dual-context attention
  attn_kernel<<<dim3(NH*BB, SQ/32), 256, 0, stream>>>(qb, kvB, vtV, ktB, vtT, hB);

  // 5. output projection + residual (f32 out), 256 blocks
  GSlot go{hB, WoB, bo, queries, (float*)d_out};
  gemm_out<<<dim3(BB*SQ/64, 8), 256, 0, stream>>>(go);
}